// Round 1
// 14712.975 us; speedup vs baseline: 1.4161x; 1.4161x over previous
//
#include <hip/hip_runtime.h>
#include <math.h>

// Problem constants
constexpr int NLAYER = 6;
constexpr int B_ = 2;
constexpr int L_ = 1024;
constexpr int D_ = 1024;
constexpr int H_ = 16;
constexpr int DH_ = 64;
constexpr int V_ = 30000;
constexpr int HID_ = 512;
constexpr int BL_ = B_ * L_;          // 2048 token rows

// bf16 / MFMA types
typedef __bf16 bf16_t;
typedef bf16_t bf16x8 __attribute__((ext_vector_type(8)));
typedef bf16_t bf16x4 __attribute__((ext_vector_type(4)));
typedef float  f32x4  __attribute__((ext_vector_type(4)));

// ---------------------------------------------------------------------------
// helpers
// ---------------------------------------------------------------------------
__device__ __forceinline__ float sigmoidf_(float z) { return 1.0f / (1.0f + expf(-z)); }
__device__ __forceinline__ float gelu_exact_(float z) {
    return 0.5f * z * (1.0f + erff(z * 0.70710678118654752440f));
}

__device__ __forceinline__ bf16x8 pack8_(const float* __restrict__ src) {
    float4 f0 = *(const float4*)(src);
    float4 f1 = *(const float4*)(src + 4);
    bf16x8 v;
    v[0] = (bf16_t)f0.x; v[1] = (bf16_t)f0.y; v[2] = (bf16_t)f0.z; v[3] = (bf16_t)f0.w;
    v[4] = (bf16_t)f1.x; v[5] = (bf16_t)f1.y; v[6] = (bf16_t)f1.z; v[7] = (bf16_t)f1.w;
    return v;
}

// block-wide reductions, blockDim.x == 256, `red` is shared float[256]
__device__ __forceinline__ float block_sum_(float v, float* red) {
    int tid = threadIdx.x;
    red[tid] = v; __syncthreads();
    #pragma unroll
    for (int s = 128; s > 0; s >>= 1) {
        if (tid < s) red[tid] += red[tid + s];
        __syncthreads();
    }
    float r = red[0];
    __syncthreads();
    return r;
}
__device__ __forceinline__ float block_max_(float v, float* red) {
    int tid = threadIdx.x;
    red[tid] = v; __syncthreads();
    #pragma unroll
    for (int s = 128; s > 0; s >>= 1) {
        if (tid < s) red[tid] = fmaxf(red[tid], red[tid + s]);
        __syncthreads();
    }
    float r = red[0];
    __syncthreads();
    return r;
}

// ---------------------------------------------------------------------------
// x = embed[ids]*sqrt(D) + pos_enc   (one block per token row)
// ---------------------------------------------------------------------------
__global__ __launch_bounds__(256) void embed_k(
    const int* __restrict__ ids, const float* __restrict__ emb,
    const float* __restrict__ pos, float* __restrict__ x)
{
    int t = blockIdx.x, tid = threadIdx.x;
    int id = ids[t];
    int l = t % L_;
    #pragma unroll
    for (int it = 0; it < 4; ++it) {
        int d = it * 256 + tid;
        x[(size_t)t * D_ + d] = emb[(size_t)id * D_ + d] * 32.0f + pos[(size_t)l * D_ + d];
    }
}

// ---------------------------------------------------------------------------
// fused: rg = sigmoid(x@rg_w + rg_b); store gs; xm = x*(1+0.1*mean(rg));
//        a_in = LayerNorm(xm, n1_g, n1_b).   One block per token row.
// ---------------------------------------------------------------------------
__global__ __launch_bounds__(256) void rg_xm_ln_k(
    const float* __restrict__ x, const float* __restrict__ rgw,
    const float* __restrict__ rgb, const float* __restrict__ g,
    const float* __restrict__ b, float* __restrict__ xm,
    float* __restrict__ ain, float* __restrict__ gs_out)
{
    int t = blockIdx.x, tid = threadIdx.x;
    __shared__ float xr[D_];
    __shared__ float red[256];
    __shared__ float rgsh[4];

    #pragma unroll
    for (int it = 0; it < 4; ++it) {
        int d = it * 256 + tid;
        xr[d] = x[(size_t)t * D_ + d];
    }
    __syncthreads();

    float a0 = 0.f, a1 = 0.f, a2 = 0.f, a3 = 0.f;
    #pragma unroll
    for (int it = 0; it < 4; ++it) {
        int d = it * 256 + tid;
        float xv = xr[d];
        float4 w = *(const float4*)(rgw + (size_t)d * 4);
        a0 += xv * w.x; a1 += xv * w.y; a2 += xv * w.z; a3 += xv * w.w;
    }
    float s0 = block_sum_(a0, red);
    float s1 = block_sum_(a1, red);
    float s2 = block_sum_(a2, red);
    float s3 = block_sum_(a3, red);
    if (tid == 0) {
        float r0 = sigmoidf_(s0 + rgb[0]);
        float r1 = sigmoidf_(s1 + rgb[1]);
        float r2 = sigmoidf_(s2 + rgb[2]);
        float r3 = sigmoidf_(s3 + rgb[3]);
        rgsh[0] = r0; rgsh[1] = r1; rgsh[2] = r2; rgsh[3] = r3;
        gs_out[(size_t)t * 4 + 0] = r0;
        gs_out[(size_t)t * 4 + 1] = r1;
        gs_out[(size_t)t * 4 + 2] = r2;
        gs_out[(size_t)t * 4 + 3] = r3;
    }
    __syncthreads();
    float factor = 1.0f + 0.025f * (rgsh[0] + rgsh[1] + rgsh[2] + rgsh[3]);

    float sm = 0.f, sq = 0.f;
    float vals[4];
    #pragma unroll
    for (int it = 0; it < 4; ++it) {
        int d = it * 256 + tid;
        float v = xr[d] * factor;
        vals[it] = v;
        xm[(size_t)t * D_ + d] = v;
        sm += v; sq += v * v;
    }
    float mean = block_sum_(sm, red) * (1.0f / D_);
    float msq  = block_sum_(sq, red) * (1.0f / D_);
    float rstd = rsqrtf(msq - mean * mean + 1e-5f);
    #pragma unroll
    for (int it = 0; it < 4; ++it) {
        int d = it * 256 + tid;
        ain[(size_t)t * D_ + d] = (vals[it] - mean) * rstd * g[d] + b[d];
    }
}

// ---------------------------------------------------------------------------
// plain LayerNorm over rows of D_  (one block per token row)
// ---------------------------------------------------------------------------
__global__ __launch_bounds__(256) void ln_k(
    const float* __restrict__ in, const float* __restrict__ g,
    const float* __restrict__ b, float* __restrict__ outp)
{
    int t = blockIdx.x, tid = threadIdx.x;
    __shared__ float red[256];
    float s1 = 0.f, s2 = 0.f;
    float vals[4];
    #pragma unroll
    for (int it = 0; it < 4; ++it) {
        int d = it * 256 + tid;
        float v = in[(size_t)t * D_ + d];
        vals[it] = v; s1 += v; s2 += v * v;
    }
    float mean = block_sum_(s1, red) * (1.0f / D_);
    float msq  = block_sum_(s2, red) * (1.0f / D_);
    float rstd = rsqrtf(msq - mean * mean + 1e-5f);
    #pragma unroll
    for (int it = 0; it < 4; ++it) {
        int d = it * 256 + tid;
        outp[(size_t)t * D_ + d] = (vals[it] - mean) * rstd * g[d] + b[d];
    }
}

// ---------------------------------------------------------------------------
// legacy f32 GEMM (kept only for the tiny phase head, N=16)
// ---------------------------------------------------------------------------
__global__ __launch_bounds__(256) void gemm_nn_k(
    const float* __restrict__ A, const float* __restrict__ W,
    const float* __restrict__ bias, const float* __restrict__ resid,
    float* __restrict__ C, int M, int N, int K,
    int act, const float* __restrict__ scale_ptr)
{
    __shared__ float As[16][65];
    __shared__ float Bs[16][64];
    const int tid = threadIdx.x;
    const int bm = blockIdx.y * 64;
    const int bn = blockIdx.x * 64;
    const int tx = tid & 15, ty = tid >> 4;
    const int ar = tid >> 2, ac = (tid & 3) << 2;
    const int br = tid >> 4, bc = (tid & 15) << 2;
    float acc[4][4] = {};

    for (int k0 = 0; k0 < K; k0 += 16) {
        float4 av = *(const float4*)(A + (size_t)(bm + ar) * K + k0 + ac);
        As[ac + 0][ar] = av.x; As[ac + 1][ar] = av.y;
        As[ac + 2][ar] = av.z; As[ac + 3][ar] = av.w;

        const float* wrow = W + (size_t)(k0 + br) * N;
        int ncol = bn + bc;
        float4 bv;
        if (ncol + 3 < N) {
            bv = *(const float4*)(wrow + ncol);
        } else {
            bv.x = (ncol + 0 < N) ? wrow[ncol + 0] : 0.f;
            bv.y = (ncol + 1 < N) ? wrow[ncol + 1] : 0.f;
            bv.z = (ncol + 2 < N) ? wrow[ncol + 2] : 0.f;
            bv.w = (ncol + 3 < N) ? wrow[ncol + 3] : 0.f;
        }
        *(float4*)(&Bs[br][bc]) = bv;
        __syncthreads();

        #pragma unroll
        for (int kk = 0; kk < 16; ++kk) {
            float a0 = As[kk][ty * 4 + 0];
            float a1 = As[kk][ty * 4 + 1];
            float a2 = As[kk][ty * 4 + 2];
            float a3 = As[kk][ty * 4 + 3];
            float4 bq = *(const float4*)(&Bs[kk][tx * 4]);
            acc[0][0] += a0 * bq.x; acc[0][1] += a0 * bq.y; acc[0][2] += a0 * bq.z; acc[0][3] += a0 * bq.w;
            acc[1][0] += a1 * bq.x; acc[1][1] += a1 * bq.y; acc[1][2] += a1 * bq.z; acc[1][3] += a1 * bq.w;
            acc[2][0] += a2 * bq.x; acc[2][1] += a2 * bq.y; acc[2][2] += a2 * bq.z; acc[2][3] += a2 * bq.w;
            acc[3][0] += a3 * bq.x; acc[3][1] += a3 * bq.y; acc[3][2] += a3 * bq.z; acc[3][3] += a3 * bq.w;
        }
        __syncthreads();
    }

    float scale = scale_ptr ? scale_ptr[0] : 1.0f;
    #pragma unroll
    for (int i = 0; i < 4; ++i) {
        int row = bm + ty * 4 + i;
        #pragma unroll
        for (int j = 0; j < 4; ++j) {
            int col = bn + tx * 4 + j;
            if (col < N) {
                float v = acc[i][j];
                if (bias) v += bias[col];
                if (act == 1)      v = gelu_exact_(v);
                else if (act == 2) v = tanhf(scale * v);
                if (resid) v += resid[(size_t)row * N + col];
                C[(size_t)row * N + col] = v;
            }
        }
    }
}

// ---------------------------------------------------------------------------
// bf16 MFMA GEMM: C[M,N] = act(A[M,K] @ B + bias) (+ resid), f32 in/out.
//   BTG=false: B = Wm[K][N] (row-major weights)       -> transpose-staged
//   BTG=true : B = Wm[N][K]^T (e.g. tied embed head)  -> direct-staged
// Tile 128xBN, BK=64; 256 threads = 4 waves; wave tile 64 x (BN/2).
// v_mfma_f32_16x16x32_bf16; f32 accumulate. LDS XOR-swizzled in 8-elem segs.
// 1D grid with grouped swizzle: MT m-tiles fastest inside n-groups of GW.
// ---------------------------------------------------------------------------
template<int BN, bool BTG>
__global__ __launch_bounds__(256) void gemm_mfma_k(
    const float* __restrict__ A, const float* __restrict__ Wm,
    const float* __restrict__ bias, const float* __restrict__ resid,
    float* __restrict__ C, int M, int N, int K, int MT, int GW,
    int act, const float* __restrict__ scale_ptr)
{
    constexpr int BM = 128;
    constexpr int BK = 64;
    constexpr int WM = 4;            // 4 x 16 rows per wave
    constexpr int WN = BN / 32;      // frags per wave in N

    __shared__ alignas(16) bf16_t As[BM][BK];
    __shared__ alignas(16) bf16_t Bs[BN][BK];

    const int tid  = threadIdx.x;
    const int lane = tid & 63;
    const int w    = tid >> 6;

    // grouped block swizzle: m-fastest within an n-group (weight tile L2-resident)
    int per = MT * GW;
    int grp = blockIdx.x / per;
    int r   = blockIdx.x % per;
    int mi  = r % MT;
    int ni  = grp * GW + r / MT;
    const int bm = mi * BM;
    const int bn = ni * BN;

    const int wr = (w & 1) * 64;
    const int wc = (w >> 1) * (BN / 2);

    const int rlo = lane & 15;
    const int lhi = lane >> 4;
    const int l7  = lane & 7;

    f32x4 acc[WM][WN];
    #pragma unroll
    for (int m = 0; m < WM; ++m)
        #pragma unroll
        for (int n = 0; n < WN; ++n) {
            f32x4 z = {0.f, 0.f, 0.f, 0.f};
            acc[m][n] = z;
        }

    for (int kt = 0; kt < K; kt += BK) {
        __syncthreads();
        // ---- stage A [BM][BK]: f32 -> bf16, 8-elem segments, seg ^= (row&7)
        #pragma unroll
        for (int i = 0; i < (BM * BK / 8) / 256; ++i) {
            int sid = i * 256 + tid;
            int row = sid >> 3;
            int s   = sid & 7;
            bf16x8 v = pack8_(A + (size_t)(bm + row) * K + kt + s * 8);
            *(bf16x8*)(&As[row][(s ^ (row & 7)) * 8]) = v;
        }
        // ---- stage B into Bs[col][k]
        if constexpr (BTG) {
            // Wm is [N][K]: rows already k-contiguous
            #pragma unroll
            for (int i = 0; i < (BN * BK / 8) / 256; ++i) {
                int sid = i * 256 + tid;
                int col = sid >> 3;
                int s   = sid & 7;
                bf16x8 v;
                if (bn + col < N) {
                    v = pack8_(Wm + (size_t)(bn + col) * K + kt + s * 8);
                } else {
                    #pragma unroll
                    for (int j = 0; j < 8; ++j) v[j] = (bf16_t)0.0f;
                }
                *(bf16x8*)(&Bs[col][(s ^ (col & 7)) * 8]) = v;
            }
        } else if constexpr (BN == 128) {
            // Wm is [K][N]: transpose 64k x 128n. thread: 8 k-rows x 4 cols.
            int col4 = (tid & 31) * 4;
            int kb   = tid >> 5;                       // 0..7
            float4 rv[8];
            #pragma unroll
            for (int j = 0; j < 8; ++j)
                rv[j] = *(const float4*)(Wm + (size_t)(kt + kb * 8 + j) * N + bn + col4);
            #pragma unroll
            for (int jj = 0; jj < 4; ++jj) {
                int col = col4 + jj;
                bf16x8 v;
                #pragma unroll
                for (int j = 0; j < 8; ++j)
                    v[j] = (bf16_t)(((const float*)&rv[j])[jj]);
                *(bf16x8*)(&Bs[col][(kb ^ (col & 7)) * 8]) = v;
            }
        } else {
            // BN == 64: transpose 64k x 64n. thread: 4 k-rows x 4 cols.
            int col4 = (tid & 15) * 4;
            int kb   = tid >> 4;                       // 0..15
            float4 rv[4];
            #pragma unroll
            for (int j = 0; j < 4; ++j)
                rv[j] = *(const float4*)(Wm + (size_t)(kt + kb * 4 + j) * N + bn + col4);
            #pragma unroll
            for (int jj = 0; jj < 4; ++jj) {
                int col = col4 + jj;
                bf16x4 v;
                #pragma unroll
                for (int j = 0; j < 4; ++j)
                    v[j] = (bf16_t)(((const float*)&rv[j])[jj]);
                *(bf16x4*)(&Bs[col][((kb >> 1) ^ (col & 7)) * 8 + (kb & 1) * 4]) = v;
            }
        }
        __syncthreads();

        // ---- compute: 2 k-halves of 32, fragments via swizzled ds_read_b128
        #pragma unroll
        for (int h = 0; h < 2; ++h) {
            int soff = ((h * 4 + lhi) ^ l7) * 8;   // row&7 == col&7 == l7 here
            bf16x8 af[WM], bfr[WN];
            #pragma unroll
            for (int m = 0; m < WM; ++m)
                af[m] = *(const bf16x8*)(&As[wr + m * 16 + rlo][soff]);
            #pragma unroll
            for (int n = 0; n < WN; ++n)
                bfr[n] = *(const bf16x8*)(&Bs[wc + n * 16 + rlo][soff]);
            #pragma unroll
            for (int m = 0; m < WM; ++m)
                #pragma unroll
                for (int n = 0; n < WN; ++n)
                    acc[m][n] = __builtin_amdgcn_mfma_f32_16x16x32_bf16(
                        af[m], bfr[n], acc[m][n], 0, 0, 0);
        }
    }

    // ---- epilogue: C/D layout col = lane&15, row = (lane>>4)*4 + reg
    float scale = scale_ptr ? scale_ptr[0] : 1.0f;
    #pragma unroll
    for (int m = 0; m < WM; ++m) {
        #pragma unroll
        for (int n = 0; n < WN; ++n) {
            int col = bn + wc + n * 16 + rlo;
            if (BTG && col >= N) continue;
            #pragma unroll
            for (int i = 0; i < 4; ++i) {
                int row = bm + wr + m * 16 + lhi * 4 + i;
                float v = acc[m][n][i];
                if (bias) v += bias[col];
                if (act == 1)      v = gelu_exact_(v);
                else if (act == 2) v = tanhf(scale * v);
                if (resid) v += resid[(size_t)row * N + col];
                C[(size_t)row * N + col] = v;
            }
        }
    }
}

// ---------------------------------------------------------------------------
// attention: one block per (lq, h, b). scores row in LDS, exact softmax.
// qkv rows: [BL, 3072] with q at col h*64+d, k at 1024+h*64+d, v at 2048+...
// ---------------------------------------------------------------------------
__global__ __launch_bounds__(256) void attn_k(
    const float* __restrict__ qkv, const float* __restrict__ pv,
    const float* __restrict__ res_scale_p, float* __restrict__ o)
{
    int lq = blockIdx.x, h = blockIdx.y, b = blockIdx.z;
    int tid = threadIdx.x;
    int tq = b * L_ + lq;

    __shared__ float qs[DH_];
    __shared__ float sc[L_];
    __shared__ float red[256];
    __shared__ float ored[256];
    __shared__ float pvq_s;

    if (tid < DH_) qs[tid] = qkv[(size_t)tq * 3072 + h * DH_ + tid];
    if (tid == 0) pvq_s = pv[(size_t)tq * H_ + h];
    __syncthreads();
    float rs = res_scale_p[0];
    float pvq = pvq_s;

    float lmax = -1e30f;
    #pragma unroll
    for (int it = 0; it < 4; ++it) {
        int m = it * 256 + tid;
        const float* kr = qkv + (size_t)(b * L_ + m) * 3072 + 1024 + h * DH_;
        float dot = 0.f;
        #pragma unroll
        for (int d4 = 0; d4 < 16; ++d4) {
            float4 kv = *(const float4*)(kr + d4 * 4);
            dot += qs[d4 * 4 + 0] * kv.x + qs[d4 * 4 + 1] * kv.y
                 + qs[d4 * 4 + 2] * kv.z + qs[d4 * 4 + 3] * kv.w;
        }
        float pd = pvq - pv[(size_t)(b * L_ + m) * H_ + h];
        float s = dot * 0.125f - rs * pd * pd;
        sc[m] = s;
        lmax = fmaxf(lmax, s);
    }
    float gmax = block_max_(lmax, red);

    float lsum = 0.f;
    #pragma unroll
    for (int it = 0; it < 4; ++it) {
        int m = it * 256 + tid;
        float p = expf(sc[m] - gmax);
        sc[m] = p;
        lsum += p;
    }
    float inv = 1.0f / block_sum_(lsum, red);
    __syncthreads();

    int d = tid & 63, chunk = tid >> 6;
    float acc = 0.f;
    int m0 = chunk * 256;
    for (int m = m0; m < m0 + 256; ++m) {
        acc += sc[m] * qkv[(size_t)(b * L_ + m) * 3072 + 2048 + h * DH_ + d];
    }
    ored[tid] = acc;
    __syncthreads();
    if (tid < DH_) {
        float v = (ored[tid] + ored[tid + 64] + ored[tid + 128] + ored[tid + 192]) * inv;
        o[(size_t)tq * D_ + h * DH_ + d] = v;
    }
}

// ---------------------------------------------------------------------------
// boundary second layer: ss[t] = sigmoid(dot(h[t], w2) + b2). block per token.
// ---------------------------------------------------------------------------
__global__ __launch_bounds__(256) void bnd2_k(
    const float* __restrict__ hbuf, const float* __restrict__ w2,
    const float* __restrict__ b2, float* __restrict__ ss_out)
{
    int t = blockIdx.x, tid = threadIdx.x;
    __shared__ float red[256];
    float acc = 0.f;
    #pragma unroll
    for (int it = 0; it < 2; ++it) {
        int d = it * 256 + tid;
        acc += hbuf[(size_t)t * HID_ + d] * w2[d];
    }
    float s = block_sum_(acc, red);
    if (tid == 0) ss_out[t] = sigmoidf_(s + b2[0]);
}

// ---------------------------------------------------------------------------
// grammar/shock means over layers
// ---------------------------------------------------------------------------
__global__ __launch_bounds__(256) void means_k(
    const float* __restrict__ gs, const float* __restrict__ ss,
    float* __restrict__ gsm, float* __restrict__ ssm)
{
    int i = blockIdx.x * 256 + threadIdx.x;
    if (i < BL_ * 4) {
        float s = 0.f;
        #pragma unroll
        for (int l = 0; l < NLAYER; ++l) s += gs[(size_t)l * BL_ * 4 + i];
        gsm[i] = s * (1.0f / NLAYER);
    }
    if (i < BL_) {
        float s = 0.f;
        #pragma unroll
        for (int l = 0; l < NLAYER; ++l) s += ss[(size_t)l * BL_ + i];
        ssm[i] = s * (1.0f / NLAYER);
    }
}

// ---------------------------------------------------------------------------
// launcher
// ---------------------------------------------------------------------------
extern "C" void kernel_launch(void* const* d_in, const int* in_sizes, int n_in,
                              void* d_out, int out_size, void* d_ws, size_t ws_size,
                              hipStream_t stream) {
    const int*   ids       = (const int*)  d_in[0];
    const float* embed     = (const float*)d_in[1];
    const float* pos_enc   = (const float*)d_in[2];
    const float* rg_w      = (const float*)d_in[3];
    const float* rg_b      = (const float*)d_in[4];
    const float* qkv_w     = (const float*)d_in[5];
    const float* qkv_b     = (const float*)d_in[6];
    const float* out_w     = (const float*)d_in[7];
    const float* out_b     = (const float*)d_in[8];
    const float* ph_w      = (const float*)d_in[9];
    const float* ph_b      = (const float*)d_in[10];
    const float* res_scale = (const float*)d_in[11];
    const float* ph_scale  = (const float*)d_in[12];
    const float* ff1_w     = (const float*)d_in[13];
    const float* ff1_b     = (const float*)d_in[14];
    const float* ff2_w     = (const float*)d_in[15];
    const float* ff2_b     = (const float*)d_in[16];
    const float* n1_g      = (const float*)d_in[17];
    const float* n1_b      = (const float*)d_in[18];
    const float* n2_g      = (const float*)d_in[19];
    const float* n2_b      = (const float*)d_in[20];
    const float* bnd_w1    = (const float*)d_in[21];
    const float* bnd_b1    = (const float*)d_in[22];
    const float* bnd_w2    = (const float*)d_in[23];
    const float* bnd_b2    = (const float*)d_in[24];
    const float* fn_g      = (const float*)d_in[25];
    const float* fn_b      = (const float*)d_in[26];

    float* out = (float*)d_out;
    float* ws  = (float*)d_ws;

    // workspace layout (floats). ffh aliases the dead qkv+attn_o region.
    const size_t M1 = 1024 * 1024;
    float* x    = ws;                    // 2M
    float* xm   = ws + 2 * M1;           // 2M
    float* ain  = ws + 4 * M1;           // 2M
    float* qkv  = ws + 6 * M1;           // 6M
    float* ao   = ws + 12 * M1;          // 2M
    float* ffh  = ws + 6 * M1;           // 8M (aliases qkv+ao, both dead by FF1)
    float* bndh = ws + 14 * M1;          // 1M
    float* pvb  = ws + 15 * M1;          // 32K
    // total: ~15.04M floats = ~60 MB

    // output offsets (floats, concatenated return order)
    const size_t o_logits = 0;
    const size_t o_x      = (size_t)BL_ * V_;
    const size_t o_gsm    = o_x + (size_t)BL_ * D_;
    const size_t o_ssm    = o_gsm + (size_t)BL_ * 4;
    const size_t o_gs     = o_ssm + (size_t)BL_;
    const size_t o_ss     = o_gs + (size_t)NLAYER * BL_ * 4;

    embed_k<<<BL_, 256, 0, stream>>>(ids, embed, pos_enc, x);

    const int MT = BL_ / 128;  // 16 m-tiles

    for (int i = 0; i < NLAYER; ++i) {
        rg_xm_ln_k<<<BL_, 256, 0, stream>>>(
            x, rg_w + (size_t)i * D_ * 4, rg_b + (size_t)i * 4,
            n1_g + (size_t)i * D_, n1_b + (size_t)i * D_,
            xm, ain, out + o_gs + (size_t)i * BL_ * 4);

        // QKV: 2048 x 3072 x 1024, bf16 MFMA (NT=24, GW=4)
        gemm_mfma_k<128, false><<<MT * 24, 256, 0, stream>>>(
            ain, qkv_w + (size_t)i * D_ * 3 * D_, qkv_b + (size_t)i * 3 * D_,
            nullptr, qkv, BL_, 3 * D_, D_, MT, 4, 0, nullptr);

        // phase head: tiny (N=16), keep f32 path
        dim3 gp(1, BL_ / 64);
        gemm_nn_k<<<gp, 256, 0, stream>>>(
            ain, ph_w + (size_t)i * D_ * H_, ph_b + (size_t)i * H_,
            nullptr, pvb, BL_, H_, D_, 2, ph_scale + i);

        dim3 ga(L_, H_, B_);
        attn_k<<<ga, 256, 0, stream>>>(qkv, pvb, res_scale + i, ao);

        // out-proj: 2048 x 1024 x 1024 (+xm resid) (NT=16, GW=4)
        gemm_mfma_k<64, false><<<MT * 16, 256, 0, stream>>>(
            ao, out_w + (size_t)i * D_ * D_, out_b + (size_t)i * D_,
            xm, x, BL_, D_, D_, MT, 4, 0, nullptr);

        ln_k<<<BL_, 256, 0, stream>>>(x, n2_g + (size_t)i * D_, n2_b + (size_t)i * D_, ain);

        // FF1: 2048 x 4096 x 1024, exact GELU (NT=32, GW=4)
        gemm_mfma_k<128, false><<<MT * 32, 256, 0, stream>>>(
            ain, ff1_w + (size_t)i * D_ * 4 * D_, ff1_b + (size_t)i * 4 * D_,
            nullptr, ffh, BL_, 4 * D_, D_, MT, 4, 1, nullptr);

        // FF2: 2048 x 1024 x 4096 (+x resid) (NT=16, GW=4)
        gemm_mfma_k<64, false><<<MT * 16, 256, 0, stream>>>(
            ffh, ff2_w + (size_t)i * 4 * D_ * D_, ff2_b + (size_t)i * D_,
            x, x, BL_, D_, 4 * D_, MT, 4, 0, nullptr);

        // boundary-1: 2048 x 512 x 1024, tanh (NT=8, GW=4)
        gemm_mfma_k<64, false><<<MT * 8, 256, 0, stream>>>(
            x, bnd_w1, bnd_b1, nullptr, bndh, BL_, HID_, D_, MT, 4, 2, nullptr);

        bnd2_k<<<BL_, 256, 0, stream>>>(bndh, bnd_w2, bnd_b2, out + o_ss + (size_t)i * BL_);
    }

    ln_k<<<BL_, 256, 0, stream>>>(x, fn_g, fn_b, out + o_x);

    // tied head: 2048 x 30000 x 1024, embed is [N][K] already (NT=235, GW=5)
    gemm_mfma_k<128, true><<<MT * 235, 256, 0, stream>>>(
        out + o_x, embed, nullptr, nullptr, out + o_logits,
        BL_, V_, D_, MT, 5, 0, nullptr);

    means_k<<<(BL_ * 4 + 255) / 256, 256, 0, stream>>>(
        out + o_gs, out + o_ss, out + o_gsm, out + o_ssm);
}

// Round 2
// 3830.552 us; speedup vs baseline: 5.4391x; 3.8410x over previous
//
#include <hip/hip_runtime.h>
#include <math.h>

// Problem constants
constexpr int NLAYER = 6;
constexpr int B_ = 2;
constexpr int L_ = 1024;
constexpr int D_ = 1024;
constexpr int H_ = 16;
constexpr int DH_ = 64;
constexpr int V_ = 30000;
constexpr int HID_ = 512;
constexpr int BL_ = B_ * L_;          // 2048 token rows

// bf16 / MFMA types
typedef __bf16 bf16_t;
typedef bf16_t bf16x8 __attribute__((ext_vector_type(8)));
typedef bf16_t bf16x4 __attribute__((ext_vector_type(4)));
typedef float  f32x4  __attribute__((ext_vector_type(4)));

// ---------------------------------------------------------------------------
// helpers
// ---------------------------------------------------------------------------
__device__ __forceinline__ float sigmoidf_(float z) { return 1.0f / (1.0f + expf(-z)); }
__device__ __forceinline__ float gelu_exact_(float z) {
    return 0.5f * z * (1.0f + erff(z * 0.70710678118654752440f));
}

__device__ __forceinline__ bf16x8 pack8_(const float* __restrict__ src) {
    float4 f0 = *(const float4*)(src);
    float4 f1 = *(const float4*)(src + 4);
    bf16x8 v;
    v[0] = (bf16_t)f0.x; v[1] = (bf16_t)f0.y; v[2] = (bf16_t)f0.z; v[3] = (bf16_t)f0.w;
    v[4] = (bf16_t)f1.x; v[5] = (bf16_t)f1.y; v[6] = (bf16_t)f1.z; v[7] = (bf16_t)f1.w;
    return v;
}
__device__ __forceinline__ bf16x8 pack8s_(const float* __restrict__ src, float sc) {
    float4 f0 = *(const float4*)(src);
    float4 f1 = *(const float4*)(src + 4);
    bf16x8 v;
    v[0] = (bf16_t)(f0.x * sc); v[1] = (bf16_t)(f0.y * sc);
    v[2] = (bf16_t)(f0.z * sc); v[3] = (bf16_t)(f0.w * sc);
    v[4] = (bf16_t)(f1.x * sc); v[5] = (bf16_t)(f1.y * sc);
    v[6] = (bf16_t)(f1.z * sc); v[7] = (bf16_t)(f1.w * sc);
    return v;
}

// block-wide reductions, blockDim.x == 256, `red` is shared float[256]
__device__ __forceinline__ float block_sum_(float v, float* red) {
    int tid = threadIdx.x;
    red[tid] = v; __syncthreads();
    #pragma unroll
    for (int s = 128; s > 0; s >>= 1) {
        if (tid < s) red[tid] += red[tid + s];
        __syncthreads();
    }
    float r = red[0];
    __syncthreads();
    return r;
}

// ---------------------------------------------------------------------------
// x = embed[ids]*sqrt(D) + pos_enc   (one block per token row)
// ---------------------------------------------------------------------------
__global__ __launch_bounds__(256) void embed_k(
    const int* __restrict__ ids, const float* __restrict__ emb,
    const float* __restrict__ pos, float* __restrict__ x)
{
    int t = blockIdx.x, tid = threadIdx.x;
    int id = ids[t];
    int l = t % L_;
    #pragma unroll
    for (int it = 0; it < 4; ++it) {
        int d = it * 256 + tid;
        x[(size_t)t * D_ + d] = emb[(size_t)id * D_ + d] * 32.0f + pos[(size_t)l * D_ + d];
    }
}

// ---------------------------------------------------------------------------
// fused: rg = sigmoid(x@rg_w + rg_b); store gs; xm = x*(1+0.1*mean(rg));
//        a_in = LayerNorm(xm, n1_g, n1_b).   One block per token row.
// ---------------------------------------------------------------------------
__global__ __launch_bounds__(256) void rg_xm_ln_k(
    const float* __restrict__ x, const float* __restrict__ rgw,
    const float* __restrict__ rgb, const float* __restrict__ g,
    const float* __restrict__ b, float* __restrict__ xm,
    float* __restrict__ ain, float* __restrict__ gs_out)
{
    int t = blockIdx.x, tid = threadIdx.x;
    __shared__ float xr[D_];
    __shared__ float red[256];
    __shared__ float rgsh[4];

    #pragma unroll
    for (int it = 0; it < 4; ++it) {
        int d = it * 256 + tid;
        xr[d] = x[(size_t)t * D_ + d];
    }
    __syncthreads();

    float a0 = 0.f, a1 = 0.f, a2 = 0.f, a3 = 0.f;
    #pragma unroll
    for (int it = 0; it < 4; ++it) {
        int d = it * 256 + tid;
        float xv = xr[d];
        float4 w = *(const float4*)(rgw + (size_t)d * 4);
        a0 += xv * w.x; a1 += xv * w.y; a2 += xv * w.z; a3 += xv * w.w;
    }
    float s0 = block_sum_(a0, red);
    float s1 = block_sum_(a1, red);
    float s2 = block_sum_(a2, red);
    float s3 = block_sum_(a3, red);
    if (tid == 0) {
        float r0 = sigmoidf_(s0 + rgb[0]);
        float r1 = sigmoidf_(s1 + rgb[1]);
        float r2 = sigmoidf_(s2 + rgb[2]);
        float r3 = sigmoidf_(s3 + rgb[3]);
        rgsh[0] = r0; rgsh[1] = r1; rgsh[2] = r2; rgsh[3] = r3;
        gs_out[(size_t)t * 4 + 0] = r0;
        gs_out[(size_t)t * 4 + 1] = r1;
        gs_out[(size_t)t * 4 + 2] = r2;
        gs_out[(size_t)t * 4 + 3] = r3;
    }
    __syncthreads();
    float factor = 1.0f + 0.025f * (rgsh[0] + rgsh[1] + rgsh[2] + rgsh[3]);

    float sm = 0.f, sq = 0.f;
    float vals[4];
    #pragma unroll
    for (int it = 0; it < 4; ++it) {
        int d = it * 256 + tid;
        float v = xr[d] * factor;
        vals[it] = v;
        xm[(size_t)t * D_ + d] = v;
        sm += v; sq += v * v;
    }
    float mean = block_sum_(sm, red) * (1.0f / D_);
    float msq  = block_sum_(sq, red) * (1.0f / D_);
    float rstd = rsqrtf(msq - mean * mean + 1e-5f);
    #pragma unroll
    for (int it = 0; it < 4; ++it) {
        int d = it * 256 + tid;
        ain[(size_t)t * D_ + d] = (vals[it] - mean) * rstd * g[d] + b[d];
    }
}

// ---------------------------------------------------------------------------
// plain LayerNorm over rows of D_  (one block per token row)
// ---------------------------------------------------------------------------
__global__ __launch_bounds__(256) void ln_k(
    const float* __restrict__ in, const float* __restrict__ g,
    const float* __restrict__ b, float* __restrict__ outp)
{
    int t = blockIdx.x, tid = threadIdx.x;
    __shared__ float red[256];
    float s1 = 0.f, s2 = 0.f;
    float vals[4];
    #pragma unroll
    for (int it = 0; it < 4; ++it) {
        int d = it * 256 + tid;
        float v = in[(size_t)t * D_ + d];
        vals[it] = v; s1 += v; s2 += v * v;
    }
    float mean = block_sum_(s1, red) * (1.0f / D_);
    float msq  = block_sum_(s2, red) * (1.0f / D_);
    float rstd = rsqrtf(msq - mean * mean + 1e-5f);
    #pragma unroll
    for (int it = 0; it < 4; ++it) {
        int d = it * 256 + tid;
        outp[(size_t)t * D_ + d] = (vals[it] - mean) * rstd * g[d] + b[d];
    }
}

// ---------------------------------------------------------------------------
// legacy f32 GEMM (kept only for the tiny phase head, N=16)
// ---------------------------------------------------------------------------
__global__ __launch_bounds__(256) void gemm_nn_k(
    const float* __restrict__ A, const float* __restrict__ W,
    const float* __restrict__ bias, const float* __restrict__ resid,
    float* __restrict__ C, int M, int N, int K,
    int act, const float* __restrict__ scale_ptr)
{
    __shared__ float As[16][65];
    __shared__ float Bs[16][64];
    const int tid = threadIdx.x;
    const int bm = blockIdx.y * 64;
    const int bn = blockIdx.x * 64;
    const int tx = tid & 15, ty = tid >> 4;
    const int ar = tid >> 2, ac = (tid & 3) << 2;
    const int br = tid >> 4, bc = (tid & 15) << 2;
    float acc[4][4] = {};

    for (int k0 = 0; k0 < K; k0 += 16) {
        float4 av = *(const float4*)(A + (size_t)(bm + ar) * K + k0 + ac);
        As[ac + 0][ar] = av.x; As[ac + 1][ar] = av.y;
        As[ac + 2][ar] = av.z; As[ac + 3][ar] = av.w;

        const float* wrow = W + (size_t)(k0 + br) * N;
        int ncol = bn + bc;
        float4 bv;
        if (ncol + 3 < N) {
            bv = *(const float4*)(wrow + ncol);
        } else {
            bv.x = (ncol + 0 < N) ? wrow[ncol + 0] : 0.f;
            bv.y = (ncol + 1 < N) ? wrow[ncol + 1] : 0.f;
            bv.z = (ncol + 2 < N) ? wrow[ncol + 2] : 0.f;
            bv.w = (ncol + 3 < N) ? wrow[ncol + 3] : 0.f;
        }
        *(float4*)(&Bs[br][bc]) = bv;
        __syncthreads();

        #pragma unroll
        for (int kk = 0; kk < 16; ++kk) {
            float a0 = As[kk][ty * 4 + 0];
            float a1 = As[kk][ty * 4 + 1];
            float a2 = As[kk][ty * 4 + 2];
            float a3 = As[kk][ty * 4 + 3];
            float4 bq = *(const float4*)(&Bs[kk][tx * 4]);
            acc[0][0] += a0 * bq.x; acc[0][1] += a0 * bq.y; acc[0][2] += a0 * bq.z; acc[0][3] += a0 * bq.w;
            acc[1][0] += a1 * bq.x; acc[1][1] += a1 * bq.y; acc[1][2] += a1 * bq.z; acc[1][3] += a1 * bq.w;
            acc[2][0] += a2 * bq.x; acc[2][1] += a2 * bq.y; acc[2][2] += a2 * bq.z; acc[2][3] += a2 * bq.w;
            acc[3][0] += a3 * bq.x; acc[3][1] += a3 * bq.y; acc[3][2] += a3 * bq.z; acc[3][3] += a3 * bq.w;
        }
        __syncthreads();
    }

    float scale = scale_ptr ? scale_ptr[0] : 1.0f;
    #pragma unroll
    for (int i = 0; i < 4; ++i) {
        int row = bm + ty * 4 + i;
        #pragma unroll
        for (int j = 0; j < 4; ++j) {
            int col = bn + tx * 4 + j;
            if (col < N) {
                float v = acc[i][j];
                if (bias) v += bias[col];
                if (act == 1)      v = gelu_exact_(v);
                else if (act == 2) v = tanhf(scale * v);
                if (resid) v += resid[(size_t)row * N + col];
                C[(size_t)row * N + col] = v;
            }
        }
    }
}

// ---------------------------------------------------------------------------
// bf16 MFMA GEMM: C[M,N] = act(A[M,K] @ B + bias) (+ resid), f32 in/out.
//   BTG=false: B = Wm[K][N] (row-major weights)       -> transpose-staged
//   BTG=true : B = Wm[N][K]^T (e.g. tied embed head)  -> direct-staged
// ---------------------------------------------------------------------------
template<int BN, bool BTG>
__global__ __launch_bounds__(256) void gemm_mfma_k(
    const float* __restrict__ A, const float* __restrict__ Wm,
    const float* __restrict__ bias, const float* __restrict__ resid,
    float* __restrict__ C, int M, int N, int K, int MT, int GW,
    int act, const float* __restrict__ scale_ptr)
{
    constexpr int BM = 128;
    constexpr int BK = 64;
    constexpr int WM = 4;            // 4 x 16 rows per wave
    constexpr int WN = BN / 32;      // frags per wave in N

    __shared__ alignas(16) bf16_t As[BM][BK];
    __shared__ alignas(16) bf16_t Bs[BN][BK];

    const int tid  = threadIdx.x;
    const int lane = tid & 63;
    const int w    = tid >> 6;

    // grouped block swizzle: m-fastest within an n-group (weight tile L2-resident)
    int per = MT * GW;
    int grp = blockIdx.x / per;
    int r   = blockIdx.x % per;
    int mi  = r % MT;
    int ni  = grp * GW + r / MT;
    const int bm = mi * BM;
    const int bn = ni * BN;

    const int wr = (w & 1) * 64;
    const int wc = (w >> 1) * (BN / 2);

    const int rlo = lane & 15;
    const int lhi = lane >> 4;
    const int l7  = lane & 7;

    f32x4 acc[WM][WN];
    #pragma unroll
    for (int m = 0; m < WM; ++m)
        #pragma unroll
        for (int n = 0; n < WN; ++n) {
            f32x4 z = {0.f, 0.f, 0.f, 0.f};
            acc[m][n] = z;
        }

    for (int kt = 0; kt < K; kt += BK) {
        __syncthreads();
        // ---- stage A [BM][BK]: f32 -> bf16, 8-elem segments, seg ^= (row&7)
        #pragma unroll
        for (int i = 0; i < (BM * BK / 8) / 256; ++i) {
            int sid = i * 256 + tid;
            int row = sid >> 3;
            int s   = sid & 7;
            bf16x8 v = pack8_(A + (size_t)(bm + row) * K + kt + s * 8);
            *(bf16x8*)(&As[row][(s ^ (row & 7)) * 8]) = v;
        }
        // ---- stage B into Bs[col][k]
        if constexpr (BTG) {
            #pragma unroll
            for (int i = 0; i < (BN * BK / 8) / 256; ++i) {
                int sid = i * 256 + tid;
                int col = sid >> 3;
                int s   = sid & 7;
                bf16x8 v;
                if (bn + col < N) {
                    v = pack8_(Wm + (size_t)(bn + col) * K + kt + s * 8);
                } else {
                    #pragma unroll
                    for (int j = 0; j < 8; ++j) v[j] = (bf16_t)0.0f;
                }
                *(bf16x8*)(&Bs[col][(s ^ (col & 7)) * 8]) = v;
            }
        } else if constexpr (BN == 128) {
            int col4 = (tid & 31) * 4;
            int kb   = tid >> 5;                       // 0..7
            float4 rv[8];
            #pragma unroll
            for (int j = 0; j < 8; ++j)
                rv[j] = *(const float4*)(Wm + (size_t)(kt + kb * 8 + j) * N + bn + col4);
            #pragma unroll
            for (int jj = 0; jj < 4; ++jj) {
                int col = col4 + jj;
                bf16x8 v;
                #pragma unroll
                for (int j = 0; j < 8; ++j)
                    v[j] = (bf16_t)(((const float*)&rv[j])[jj]);
                *(bf16x8*)(&Bs[col][(kb ^ (col & 7)) * 8]) = v;
            }
        } else {
            int col4 = (tid & 15) * 4;
            int kb   = tid >> 4;                       // 0..15
            float4 rv[4];
            #pragma unroll
            for (int j = 0; j < 4; ++j)
                rv[j] = *(const float4*)(Wm + (size_t)(kt + kb * 4 + j) * N + bn + col4);
            #pragma unroll
            for (int jj = 0; jj < 4; ++jj) {
                int col = col4 + jj;
                bf16x4 v;
                #pragma unroll
                for (int j = 0; j < 4; ++j)
                    v[j] = (bf16_t)(((const float*)&rv[j])[jj]);
                *(bf16x4*)(&Bs[col][((kb >> 1) ^ (col & 7)) * 8 + (kb & 1) * 4]) = v;
            }
        }
        __syncthreads();

        // ---- compute: 2 k-halves of 32, fragments via swizzled ds_read_b128
        #pragma unroll
        for (int h = 0; h < 2; ++h) {
            int soff = ((h * 4 + lhi) ^ l7) * 8;
            bf16x8 af[WM], bfr[WN];
            #pragma unroll
            for (int m = 0; m < WM; ++m)
                af[m] = *(const bf16x8*)(&As[wr + m * 16 + rlo][soff]);
            #pragma unroll
            for (int n = 0; n < WN; ++n)
                bfr[n] = *(const bf16x8*)(&Bs[wc + n * 16 + rlo][soff]);
            #pragma unroll
            for (int m = 0; m < WM; ++m)
                #pragma unroll
                for (int n = 0; n < WN; ++n)
                    acc[m][n] = __builtin_amdgcn_mfma_f32_16x16x32_bf16(
                        af[m], bfr[n], acc[m][n], 0, 0, 0);
        }
    }

    // ---- epilogue: C/D layout col = lane&15, row = (lane>>4)*4 + reg
    float scale = scale_ptr ? scale_ptr[0] : 1.0f;
    #pragma unroll
    for (int m = 0; m < WM; ++m) {
        #pragma unroll
        for (int n = 0; n < WN; ++n) {
            int col = bn + wc + n * 16 + rlo;
            if (BTG && col >= N) continue;
            #pragma unroll
            for (int i = 0; i < 4; ++i) {
                int row = bm + wr + m * 16 + lhi * 4 + i;
                float v = acc[m][n][i];
                if (bias) v += bias[col];
                if (act == 1)      v = gelu_exact_(v);
                else if (act == 2) v = tanhf(scale * v);
                if (resid) v += resid[(size_t)row * N + col];
                C[(size_t)row * N + col] = v;
            }
        }
    }
}

// ---------------------------------------------------------------------------
// flash-style MFMA attention. Grid: (L/64, H, B). 256 threads = 4 waves.
// Block handles 64 query rows for one (b,h); each wave owns 16 rows.
// KV tiled by 64 keys: K staged direct [key][d], V staged transposed [d][key],
// both bf16 + XOR-swizzled (same scheme as gemm_mfma_k). Online softmax with
// phase bias s = (q.k)/8 - rs*(pvq-pvk)^2 (q pre-scaled by 1/8).
// P goes C-layout -> A-fragment layout via a wave-private swizzled LDS tile.
// ---------------------------------------------------------------------------
__global__ __launch_bounds__(256) void attn_mfma_k(
    const float* __restrict__ qkv, const float* __restrict__ pv,
    const float* __restrict__ res_scale_p, float* __restrict__ o)
{
    constexpr int QB = 64;
    constexpr int NB = 64;

    __shared__ alignas(16) bf16_t Ks[NB][DH_];     // [key][d]
    __shared__ alignas(16) bf16_t Vt[DH_][NB];     // [d][key]
    __shared__ alignas(16) bf16_t Pl[4][16][NB];   // wave-private P tiles
    __shared__ float pvq_s[QB];
    __shared__ float pvk_s[NB];

    const int qt = blockIdx.x, h = blockIdx.y, b = blockIdx.z;
    const int tid = threadIdx.x;
    const int lane = tid & 63, w = tid >> 6;
    const int rlo = lane & 15, lhi = lane >> 4, l7 = lane & 7;
    const float rs = res_scale_p[0];

    const size_t rowbase = (size_t)(b * L_ + qt * QB);

    // Q fragments (pre-scaled by 1/8): A-frag row = rlo, k = kk*32 + lhi*8 + j
    bf16x8 qf[2];
    {
        const float* qrow = qkv + (rowbase + w * 16 + rlo) * 3072 + h * DH_;
        #pragma unroll
        for (int kk = 0; kk < 2; ++kk)
            qf[kk] = pack8s_(qrow + kk * 32 + lhi * 8, 0.125f);
    }
    if (tid < QB) pvq_s[tid] = pv[(rowbase + tid) * H_ + h];

    float m_r[4], l_r[4];
    f32x4 acc_o[4];
    #pragma unroll
    for (int r = 0; r < 4; ++r) { m_r[r] = -1e30f; l_r[r] = 0.f; }
    #pragma unroll
    for (int n = 0; n < 4; ++n) {
        f32x4 z = {0.f, 0.f, 0.f, 0.f};
        acc_o[n] = z;
    }

    bf16_t* pw = &Pl[w][0][0];

    for (int k0 = 0; k0 < L_; k0 += NB) {
        __syncthreads();
        // ---- stage K tile [64 key][64 d], swizzled like gemm As
        #pragma unroll
        for (int i = 0; i < 2; ++i) {
            int sid = i * 256 + tid;
            int row = sid >> 3, s = sid & 7;
            bf16x8 v = pack8_(qkv + (size_t)(b * L_ + k0 + row) * 3072 + 1024 + h * DH_ + s * 8);
            *(bf16x8*)(&Ks[row][(s ^ (row & 7)) * 8]) = v;
        }
        // ---- stage V transposed [64 d][64 key], swizzled like gemm Bs (BN=64)
        {
            int col4 = (tid & 15) * 4;      // d
            int kb   = tid >> 4;            // 0..15, 4 keys each
            float4 rv[4];
            #pragma unroll
            for (int j = 0; j < 4; ++j)
                rv[j] = *(const float4*)(qkv + (size_t)(b * L_ + k0 + kb * 4 + j) * 3072
                                         + 2048 + h * DH_ + col4);
            #pragma unroll
            for (int jj = 0; jj < 4; ++jj) {
                int col = col4 + jj;
                bf16x4 v;
                #pragma unroll
                for (int j = 0; j < 4; ++j)
                    v[j] = (bf16_t)(((const float*)&rv[j])[jj]);
                *(bf16x4*)(&Vt[col][((kb >> 1) ^ (col & 7)) * 8 + (kb & 1) * 4]) = v;
            }
        }
        if (tid < NB) pvk_s[tid] = pv[(size_t)(b * L_ + k0 + tid) * H_ + h];
        __syncthreads();

        // ---- S = (Q/8) @ K^T : 4 key-frags x 2 k-chunks
        f32x4 sacc[4];
        #pragma unroll
        for (int n = 0; n < 4; ++n) {
            f32x4 z = {0.f, 0.f, 0.f, 0.f};
            sacc[n] = z;
        }
        #pragma unroll
        for (int kk = 0; kk < 2; ++kk) {
            int soff = ((kk * 4 + lhi) ^ l7) * 8;
            bf16x8 kf[4];
            #pragma unroll
            for (int n = 0; n < 4; ++n)
                kf[n] = *(const bf16x8*)(&Ks[n * 16 + rlo][soff]);
            #pragma unroll
            for (int n = 0; n < 4; ++n)
                sacc[n] = __builtin_amdgcn_mfma_f32_16x16x32_bf16(
                    qf[kk], kf[n], sacc[n], 0, 0, 0);
        }

        // ---- phase bias + tile max (C layout: row q = lhi*4+r, col key = n*16+rlo)
        float sv[4][4];
        float tmax[4] = {-1e30f, -1e30f, -1e30f, -1e30f};
        #pragma unroll
        for (int n = 0; n < 4; ++n) {
            float pvk = pvk_s[n * 16 + rlo];
            #pragma unroll
            for (int r = 0; r < 4; ++r) {
                float dd = pvq_s[w * 16 + lhi * 4 + r] - pvk;
                float s = sacc[n][r] - rs * dd * dd;
                sv[n][r] = s;
                tmax[r] = fmaxf(tmax[r], s);
            }
        }
        #pragma unroll
        for (int st = 1; st < 16; st <<= 1)
            #pragma unroll
            for (int r = 0; r < 4; ++r)
                tmax[r] = fmaxf(tmax[r], __shfl_xor(tmax[r], st));

        // ---- online softmax update
        float tsum[4] = {0.f, 0.f, 0.f, 0.f};
        #pragma unroll
        for (int r = 0; r < 4; ++r) {
            float mn = fmaxf(m_r[r], tmax[r]);
            float sc = expf(m_r[r] - mn);
            m_r[r] = mn;
            l_r[r] *= sc;
            #pragma unroll
            for (int n = 0; n < 4; ++n) acc_o[n][r] *= sc;
        }
        #pragma unroll
        for (int n = 0; n < 4; ++n) {
            int key = n * 16 + rlo;
            #pragma unroll
            for (int r = 0; r < 4; ++r) {
                float p = expf(sv[n][r] - m_r[r]);
                tsum[r] += p;
                int q = lhi * 4 + r;
                pw[q * NB + (((key >> 3) ^ (q & 7)) * 8 + (key & 7))] = (bf16_t)p;
            }
        }
        #pragma unroll
        for (int st = 1; st < 16; st <<= 1)
            #pragma unroll
            for (int r = 0; r < 4; ++r)
                tsum[r] += __shfl_xor(tsum[r], st);
        #pragma unroll
        for (int r = 0; r < 4; ++r) l_r[r] += tsum[r];

        // ---- O += P @ V : A-frag P from wave-private LDS, B-frag from Vt
        #pragma unroll
        for (int kk = 0; kk < 2; ++kk) {
            int soff = ((kk * 4 + lhi) ^ l7) * 8;
            bf16x8 pa = *(const bf16x8*)(pw + rlo * NB + (((kk * 4 + lhi) ^ (rlo & 7)) * 8));
            bf16x8 vf[4];
            #pragma unroll
            for (int n = 0; n < 4; ++n)
                vf[n] = *(const bf16x8*)(&Vt[n * 16 + rlo][soff]);
            #pragma unroll
            for (int n = 0; n < 4; ++n)
                acc_o[n] = __builtin_amdgcn_mfma_f32_16x16x32_bf16(
                    pa, vf[n], acc_o[n], 0, 0, 0);
        }
    }

    // ---- normalize and write: row q = lhi*4+r, col d = n*16+rlo
    float inv[4];
    #pragma unroll
    for (int r = 0; r < 4; ++r) inv[r] = 1.0f / l_r[r];
    #pragma unroll
    for (int n = 0; n < 4; ++n)
        #pragma unroll
        for (int r = 0; r < 4; ++r)
            o[(rowbase + w * 16 + lhi * 4 + r) * D_ + h * DH_ + n * 16 + rlo] =
                acc_o[n][r] * inv[r];
}

// ---------------------------------------------------------------------------
// boundary second layer: ss[t] = sigmoid(dot(h[t], w2) + b2). block per token.
// ---------------------------------------------------------------------------
__global__ __launch_bounds__(256) void bnd2_k(
    const float* __restrict__ hbuf, const float* __restrict__ w2,
    const float* __restrict__ b2, float* __restrict__ ss_out)
{
    int t = blockIdx.x, tid = threadIdx.x;
    __shared__ float red[256];
    float acc = 0.f;
    #pragma unroll
    for (int it = 0; it < 2; ++it) {
        int d = it * 256 + tid;
        acc += hbuf[(size_t)t * HID_ + d] * w2[d];
    }
    float s = block_sum_(acc, red);
    if (tid == 0) ss_out[t] = sigmoidf_(s + b2[0]);
}

// ---------------------------------------------------------------------------
// grammar/shock means over layers
// ---------------------------------------------------------------------------
__global__ __launch_bounds__(256) void means_k(
    const float* __restrict__ gs, const float* __restrict__ ss,
    float* __restrict__ gsm, float* __restrict__ ssm)
{
    int i = blockIdx.x * 256 + threadIdx.x;
    if (i < BL_ * 4) {
        float s = 0.f;
        #pragma unroll
        for (int l = 0; l < NLAYER; ++l) s += gs[(size_t)l * BL_ * 4 + i];
        gsm[i] = s * (1.0f / NLAYER);
    }
    if (i < BL_) {
        float s = 0.f;
        #pragma unroll
        for (int l = 0; l < NLAYER; ++l) s += ss[(size_t)l * BL_ + i];
        ssm[i] = s * (1.0f / NLAYER);
    }
}

// ---------------------------------------------------------------------------
// launcher
// ---------------------------------------------------------------------------
extern "C" void kernel_launch(void* const* d_in, const int* in_sizes, int n_in,
                              void* d_out, int out_size, void* d_ws, size_t ws_size,
                              hipStream_t stream) {
    const int*   ids       = (const int*)  d_in[0];
    const float* embed     = (const float*)d_in[1];
    const float* pos_enc   = (const float*)d_in[2];
    const float* rg_w      = (const float*)d_in[3];
    const float* rg_b      = (const float*)d_in[4];
    const float* qkv_w     = (const float*)d_in[5];
    const float* qkv_b     = (const float*)d_in[6];
    const float* out_w     = (const float*)d_in[7];
    const float* out_b     = (const float*)d_in[8];
    const float* ph_w      = (const float*)d_in[9];
    const float* ph_b      = (const float*)d_in[10];
    const float* res_scale = (const float*)d_in[11];
    const float* ph_scale  = (const float*)d_in[12];
    const float* ff1_w     = (const float*)d_in[13];
    const float* ff1_b     = (const float*)d_in[14];
    const float* ff2_w     = (const float*)d_in[15];
    const float* ff2_b     = (const float*)d_in[16];
    const float* n1_g      = (const float*)d_in[17];
    const float* n1_b      = (const float*)d_in[18];
    const float* n2_g      = (const float*)d_in[19];
    const float* n2_b      = (const float*)d_in[20];
    const float* bnd_w1    = (const float*)d_in[21];
    const float* bnd_b1    = (const float*)d_in[22];
    const float* bnd_w2    = (const float*)d_in[23];
    const float* bnd_b2    = (const float*)d_in[24];
    const float* fn_g      = (const float*)d_in[25];
    const float* fn_b      = (const float*)d_in[26];

    float* out = (float*)d_out;
    float* ws  = (float*)d_ws;

    // workspace layout (floats). ffh aliases the dead qkv+attn_o region.
    const size_t M1 = 1024 * 1024;
    float* x    = ws;                    // 2M
    float* xm   = ws + 2 * M1;           // 2M
    float* ain  = ws + 4 * M1;           // 2M
    float* qkv  = ws + 6 * M1;           // 6M
    float* ao   = ws + 12 * M1;          // 2M
    float* ffh  = ws + 6 * M1;           // 8M (aliases qkv+ao, both dead by FF1)
    float* bndh = ws + 14 * M1;          // 1M
    float* pvb  = ws + 15 * M1;          // 32K

    // output offsets (floats, concatenated return order)
    const size_t o_logits = 0;
    const size_t o_x      = (size_t)BL_ * V_;
    const size_t o_gsm    = o_x + (size_t)BL_ * D_;
    const size_t o_ssm    = o_gsm + (size_t)BL_ * 4;
    const size_t o_gs     = o_ssm + (size_t)BL_;
    const size_t o_ss     = o_gs + (size_t)NLAYER * BL_ * 4;

    embed_k<<<BL_, 256, 0, stream>>>(ids, embed, pos_enc, x);

    const int MT = BL_ / 128;  // 16 m-tiles

    for (int i = 0; i < NLAYER; ++i) {
        rg_xm_ln_k<<<BL_, 256, 0, stream>>>(
            x, rg_w + (size_t)i * D_ * 4, rg_b + (size_t)i * 4,
            n1_g + (size_t)i * D_, n1_b + (size_t)i * D_,
            xm, ain, out + o_gs + (size_t)i * BL_ * 4);

        // QKV: 2048 x 3072 x 1024
        gemm_mfma_k<128, false><<<MT * 24, 256, 0, stream>>>(
            ain, qkv_w + (size_t)i * D_ * 3 * D_, qkv_b + (size_t)i * 3 * D_,
            nullptr, qkv, BL_, 3 * D_, D_, MT, 4, 0, nullptr);

        // phase head: tiny (N=16), keep f32 path
        dim3 gp(1, BL_ / 64);
        gemm_nn_k<<<gp, 256, 0, stream>>>(
            ain, ph_w + (size_t)i * D_ * H_, ph_b + (size_t)i * H_,
            nullptr, pvb, BL_, H_, D_, 2, ph_scale + i);

        dim3 ga(L_ / 64, H_, B_);
        attn_mfma_k<<<ga, 256, 0, stream>>>(qkv, pvb, res_scale + i, ao);

        // out-proj: 2048 x 1024 x 1024 (+xm resid)
        gemm_mfma_k<64, false><<<MT * 16, 256, 0, stream>>>(
            ao, out_w + (size_t)i * D_ * D_, out_b + (size_t)i * D_,
            xm, x, BL_, D_, D_, MT, 4, 0, nullptr);

        ln_k<<<BL_, 256, 0, stream>>>(x, n2_g + (size_t)i * D_, n2_b + (size_t)i * D_, ain);

        // FF1: 2048 x 4096 x 1024, exact GELU
        gemm_mfma_k<128, false><<<MT * 32, 256, 0, stream>>>(
            ain, ff1_w + (size_t)i * D_ * 4 * D_, ff1_b + (size_t)i * 4 * D_,
            nullptr, ffh, BL_, 4 * D_, D_, MT, 4, 1, nullptr);

        // FF2: 2048 x 1024 x 4096 (+x resid)
        gemm_mfma_k<64, false><<<MT * 16, 256, 0, stream>>>(
            ffh, ff2_w + (size_t)i * 4 * D_ * D_, ff2_b + (size_t)i * D_,
            x, x, BL_, D_, 4 * D_, MT, 4, 0, nullptr);

        // boundary-1: 2048 x 512 x 1024, tanh
        gemm_mfma_k<64, false><<<MT * 8, 256, 0, stream>>>(
            x, bnd_w1, bnd_b1, nullptr, bndh, BL_, HID_, D_, MT, 4, 2, nullptr);

        bnd2_k<<<BL_, 256, 0, stream>>>(bndh, bnd_w2, bnd_b2, out + o_ss + (size_t)i * BL_);
    }

    ln_k<<<BL_, 256, 0, stream>>>(x, fn_g, fn_b, out + o_x);

    // tied head: 2048 x 30000 x 1024, embed is [N][K] already
    gemm_mfma_k<128, true><<<MT * 235, 256, 0, stream>>>(
        out + o_x, embed, nullptr, nullptr, out + o_logits,
        BL_, V_, D_, MT, 5, 0, nullptr);

    means_k<<<(BL_ * 4 + 255) / 256, 256, 0, stream>>>(
        out + o_gs, out + o_ss, out + o_gsm, out + o_ssm);
}

// Round 3
// 2658.947 us; speedup vs baseline: 7.8358x; 1.4406x over previous
//
#include <hip/hip_runtime.h>
#include <math.h>

// Problem constants
constexpr int NLAYER = 6;
constexpr int B_ = 2;
constexpr int L_ = 1024;
constexpr int D_ = 1024;
constexpr int H_ = 16;
constexpr int DH_ = 64;
constexpr int V_ = 30000;
constexpr int HID_ = 512;
constexpr int BL_ = B_ * L_;          // 2048 token rows

// bf16 / MFMA types
typedef __bf16 bf16_t;
typedef bf16_t bf16x8 __attribute__((ext_vector_type(8)));
typedef bf16_t bf16x4 __attribute__((ext_vector_type(4)));
typedef float  f32x4  __attribute__((ext_vector_type(4)));

// global->LDS direct staging, 16B per lane. LDS dest is wave-uniform base;
// HW writes base + lane*16. Global addr is per-lane.
#define GLOAD_LDS16(gp, lp)                                                    \
    __builtin_amdgcn_global_load_lds(                                          \
        (const __attribute__((address_space(1))) void*)(gp),                   \
        (__attribute__((address_space(3))) void*)(lp), 16, 0, 0)

// ---------------------------------------------------------------------------
// helpers
// ---------------------------------------------------------------------------
__device__ __forceinline__ float sigmoidf_(float z) { return 1.0f / (1.0f + expf(-z)); }
__device__ __forceinline__ float gelu_exact_(float z) {
    return 0.5f * z * (1.0f + erff(z * 0.70710678118654752440f));
}

__device__ __forceinline__ bf16x8 pack8_(const float* __restrict__ src) {
    float4 f0 = *(const float4*)(src);
    float4 f1 = *(const float4*)(src + 4);
    bf16x8 v;
    v[0] = (bf16_t)f0.x; v[1] = (bf16_t)f0.y; v[2] = (bf16_t)f0.z; v[3] = (bf16_t)f0.w;
    v[4] = (bf16_t)f1.x; v[5] = (bf16_t)f1.y; v[6] = (bf16_t)f1.z; v[7] = (bf16_t)f1.w;
    return v;
}

// block-wide sum, blockDim.x == 256, `red` is shared float[256]
__device__ __forceinline__ float block_sum_(float v, float* red) {
    int tid = threadIdx.x;
    red[tid] = v; __syncthreads();
    #pragma unroll
    for (int s = 128; s > 0; s >>= 1) {
        if (tid < s) red[tid] += red[tid + s];
        __syncthreads();
    }
    float r = red[0];
    __syncthreads();
    return r;
}

// ---------------------------------------------------------------------------
// x = embed[ids]*sqrt(D) + pos_enc   (one block per token row)
// ---------------------------------------------------------------------------
__global__ __launch_bounds__(256) void embed_k(
    const int* __restrict__ ids, const float* __restrict__ emb,
    const float* __restrict__ pos, float* __restrict__ x)
{
    int t = blockIdx.x, tid = threadIdx.x;
    int id = ids[t];
    int l = t % L_;
    #pragma unroll
    for (int it = 0; it < 4; ++it) {
        int d = it * 256 + tid;
        x[(size_t)t * D_ + d] = emb[(size_t)id * D_ + d] * 32.0f + pos[(size_t)l * D_ + d];
    }
}

// ---------------------------------------------------------------------------
// weight transpose+convert: up to 4 tensors, f32 src[K][N] -> bf16 dst[N][K].
// 32x32 tiles via LDS; blockIdx ranges select the tensor (c* are cumulative).
// ---------------------------------------------------------------------------
__global__ __launch_bounds__(256) void tcw_k(
    const float* s0, bf16_t* d0, int K0, int N0, int c0,
    const float* s1, bf16_t* d1, int K1, int N1, int c1,
    const float* s2, bf16_t* d2, int K2, int N2, int c2,
    const float* s3, bf16_t* d3, int K3, int N3, int c3)
{
    __shared__ float t32[32][33];
    int bid = blockIdx.x;
    const float* s; bf16_t* d; int K, N, base;
    if (bid < c0)      { s = s0; d = d0; K = K0; N = N0; base = 0; }
    else if (bid < c1) { s = s1; d = d1; K = K1; N = N1; base = c0; }
    else if (bid < c2) { s = s2; d = d2; K = K2; N = N2; base = c1; }
    else               { s = s3; d = d3; K = K3; N = N3; base = c2; }
    int tt = bid - base;
    int KT = K >> 5;
    int kt = tt % KT, nt = tt / KT;
    int tid = threadIdx.x, cx = tid & 31, ry = tid >> 5;
    #pragma unroll
    for (int j = 0; j < 4; ++j)
        t32[ry + 8 * j][cx] = s[(size_t)(kt * 32 + ry + 8 * j) * N + nt * 32 + cx];
    __syncthreads();
    #pragma unroll
    for (int j = 0; j < 4; ++j)
        d[(size_t)(nt * 32 + ry + 8 * j) * K + kt * 32 + cx] =
            (bf16_t)t32[cx][ry + 8 * j];
}

// ---------------------------------------------------------------------------
// straight f32 -> bf16 convert (8 elems/thread, grid-stride)
// ---------------------------------------------------------------------------
__global__ __launch_bounds__(256) void cvtb_k(
    const float* __restrict__ s, bf16_t* __restrict__ d, int n8)
{
    for (int i = blockIdx.x * 256 + threadIdx.x; i < n8; i += gridDim.x * 256)
        *(bf16x8*)(d + (size_t)i * 8) = pack8_(s + (size_t)i * 8);
}

// ---------------------------------------------------------------------------
// fused: rg = sigmoid(x@rg_w + rg_b); store gs; xm = x*(1+0.1*mean(rg));
//        a_in = LayerNorm(xm) -> ainb (bf16);
//        pv = tanh(ps * (a_in @ ph_w + ph_b)) -> pvb.  One block per token.
// ---------------------------------------------------------------------------
__global__ __launch_bounds__(256) void rg_xm_ln_k(
    const float* __restrict__ x, const float* __restrict__ rgw,
    const float* __restrict__ rgb, const float* __restrict__ g,
    const float* __restrict__ b, const float* __restrict__ phw,
    const float* __restrict__ phb, const float* __restrict__ ps_p,
    float* __restrict__ xm, bf16_t* __restrict__ ainb,
    float* __restrict__ pvb, float* __restrict__ gs_out)
{
    int t = blockIdx.x, tid = threadIdx.x;
    __shared__ float xr[D_];
    __shared__ float red[256];
    __shared__ float rgsh[4];

    #pragma unroll
    for (int it = 0; it < 4; ++it) {
        int d = it * 256 + tid;
        xr[d] = x[(size_t)t * D_ + d];
    }
    __syncthreads();

    float a0 = 0.f, a1 = 0.f, a2 = 0.f, a3 = 0.f;
    #pragma unroll
    for (int it = 0; it < 4; ++it) {
        int d = it * 256 + tid;
        float xv = xr[d];
        float4 w = *(const float4*)(rgw + (size_t)d * 4);
        a0 += xv * w.x; a1 += xv * w.y; a2 += xv * w.z; a3 += xv * w.w;
    }
    float s0 = block_sum_(a0, red);
    float s1 = block_sum_(a1, red);
    float s2 = block_sum_(a2, red);
    float s3 = block_sum_(a3, red);
    if (tid == 0) {
        float r0 = sigmoidf_(s0 + rgb[0]);
        float r1 = sigmoidf_(s1 + rgb[1]);
        float r2 = sigmoidf_(s2 + rgb[2]);
        float r3 = sigmoidf_(s3 + rgb[3]);
        rgsh[0] = r0; rgsh[1] = r1; rgsh[2] = r2; rgsh[3] = r3;
        gs_out[(size_t)t * 4 + 0] = r0;
        gs_out[(size_t)t * 4 + 1] = r1;
        gs_out[(size_t)t * 4 + 2] = r2;
        gs_out[(size_t)t * 4 + 3] = r3;
    }
    __syncthreads();
    float factor = 1.0f + 0.025f * (rgsh[0] + rgsh[1] + rgsh[2] + rgsh[3]);

    float sm = 0.f, sq = 0.f;
    float vals[4];
    #pragma unroll
    for (int it = 0; it < 4; ++it) {
        int d = it * 256 + tid;
        float v = xr[d] * factor;
        vals[it] = v;
        xm[(size_t)t * D_ + d] = v;
        sm += v; sq += v * v;
    }
    float mean = block_sum_(sm, red) * (1.0f / D_);
    float msq  = block_sum_(sq, red) * (1.0f / D_);
    float rstd = rsqrtf(msq - mean * mean + 1e-5f);
    #pragma unroll
    for (int it = 0; it < 4; ++it) {
        int d = it * 256 + tid;
        float a = (vals[it] - mean) * rstd * g[d] + b[d];
        ainb[(size_t)t * D_ + d] = (bf16_t)a;
        xr[d] = a;                      // keep LN output for phase GEMV
    }
    __syncthreads();

    // phase GEMV: col c = tid&15, k-chunk grp = tid>>4 (64 k each)
    {
        int c = tid & 15, grp = tid >> 4;
        float acc = 0.f;
        int k0 = grp * 64;
        #pragma unroll
        for (int kk = 0; kk < 64; ++kk)
            acc += xr[k0 + kk] * phw[(size_t)(k0 + kk) * H_ + c];
        red[tid] = acc;
        __syncthreads();
        if (tid < 16) {
            float s = 0.f;
            #pragma unroll
            for (int gg = 0; gg < 16; ++gg) s += red[gg * 16 + tid];
            pvb[(size_t)t * H_ + tid] = tanhf(ps_p[0] * (s + phb[tid]));
        }
    }
}

// ---------------------------------------------------------------------------
// LayerNorm over rows of D_; writes f32 (optional) and/or bf16 (optional).
// ---------------------------------------------------------------------------
__global__ __launch_bounds__(256) void ln_k(
    const float* __restrict__ in, const float* __restrict__ g,
    const float* __restrict__ b, float* __restrict__ outp,
    bf16_t* __restrict__ outb)
{
    int t = blockIdx.x, tid = threadIdx.x;
    __shared__ float red[256];
    float s1 = 0.f, s2 = 0.f;
    float vals[4];
    #pragma unroll
    for (int it = 0; it < 4; ++it) {
        int d = it * 256 + tid;
        float v = in[(size_t)t * D_ + d];
        vals[it] = v; s1 += v; s2 += v * v;
    }
    float mean = block_sum_(s1, red) * (1.0f / D_);
    float msq  = block_sum_(s2, red) * (1.0f / D_);
    float rstd = rsqrtf(msq - mean * mean + 1e-5f);
    #pragma unroll
    for (int it = 0; it < 4; ++it) {
        int d = it * 256 + tid;
        float v = (vals[it] - mean) * rstd * g[d] + b[d];
        if (outp) outp[(size_t)t * D_ + d] = v;
        if (outb) outb[(size_t)t * D_ + d] = (bf16_t)v;
    }
}

// ---------------------------------------------------------------------------
// bf16 MFMA GEMM (m97 structure): C = act(A @ B^T + bias) (+resid)
//   A: bf16 [M][K] row-major; Bm: bf16 [N][K] row-major (k-contiguous).
//   global_load_lds dwordx4 staging into linear LDS; ds_read_b128 fragments.
// Tile 128xBN, BK=64; 256 threads = 4 waves; wave tile 64 x (BN/2).
// C: optional f32 out (+bias/act/resid), Cb: optional bf16 out.
// ---------------------------------------------------------------------------
template<int BN>
__global__ __launch_bounds__(256) void gemm_bf_k(
    const bf16_t* __restrict__ A, const bf16_t* __restrict__ Bm,
    const float* __restrict__ bias, const float* __restrict__ resid,
    float* __restrict__ C, bf16_t* __restrict__ Cb,
    int M, int N, int K, int MT, int GW,
    int act, const float* __restrict__ scale_ptr)
{
    constexpr int BM = 128;
    constexpr int BK = 64;
    constexpr int WN = BN / 32;      // n-frags per wave

    __shared__ alignas(16) bf16_t As[BM][BK];
    __shared__ alignas(16) bf16_t Bs[BN][BK];

    const int tid  = threadIdx.x;
    const int lane = tid & 63;
    const int w    = tid >> 6;

    // grouped block swizzle: m-fastest within an n-group (weight tile L2-resident)
    int per = MT * GW;
    int grp = blockIdx.x / per;
    int r   = blockIdx.x % per;
    int mi  = r % MT;
    int ni  = grp * GW + r / MT;
    const int bm = mi * BM;
    const int bn = ni * BN;

    const int wr = (w & 1) * 64;
    const int wc = (w >> 1) * (BN / 2);
    const int rlo = lane & 15, lhi = lane >> 4;
    const int srow = lane >> 3;          // staging: row within 8-row slab
    const int scol = (lane & 7) * 8;     // staging: elem offset (16B chunk)

    f32x4 acc[4][WN];
    #pragma unroll
    for (int m = 0; m < 4; ++m)
        #pragma unroll
        for (int n = 0; n < WN; ++n) {
            f32x4 z = {0.f, 0.f, 0.f, 0.f};
            acc[m][n] = z;
        }

    for (int kt = 0; kt < K; kt += BK) {
        __syncthreads();
        // ---- stage A: 16 slabs of 8 rows, 4 per wave
        #pragma unroll
        for (int i = 0; i < 4; ++i) {
            int is = w * 4 + i;
            const bf16_t* gp = A + (size_t)(bm + is * 8 + srow) * K + kt + scol;
            GLOAD_LDS16(gp, &As[is * 8][0]);
        }
        // ---- stage B: BN/8 slabs, row-clamped for N edge
        #pragma unroll
        for (int i = 0; i < BN / 32; ++i) {
            int is = w * (BN / 32) + i;
            int row = bn + is * 8 + srow;
            if (row > N - 1) row = N - 1;
            const bf16_t* gp = Bm + (size_t)row * K + kt + scol;
            GLOAD_LDS16(gp, &Bs[is * 8][0]);
        }
        __syncthreads();

        // ---- compute: 2 k-halves of 32
        #pragma unroll
        for (int h2 = 0; h2 < 2; ++h2) {
            int ko = h2 * 32 + lhi * 8;
            bf16x8 af[4], bfr[WN];
            #pragma unroll
            for (int m = 0; m < 4; ++m)
                af[m] = *(const bf16x8*)(&As[wr + m * 16 + rlo][ko]);
            #pragma unroll
            for (int n = 0; n < WN; ++n)
                bfr[n] = *(const bf16x8*)(&Bs[wc + n * 16 + rlo][ko]);
            #pragma unroll
            for (int m = 0; m < 4; ++m)
                #pragma unroll
                for (int n = 0; n < WN; ++n)
                    acc[m][n] = __builtin_amdgcn_mfma_f32_16x16x32_bf16(
                        af[m], bfr[n], acc[m][n], 0, 0, 0);
        }
    }

    // ---- epilogue: C/D layout col = lane&15, row = (lane>>4)*4 + reg
    float scale = scale_ptr ? scale_ptr[0] : 1.0f;
    #pragma unroll
    for (int m = 0; m < 4; ++m) {
        #pragma unroll
        for (int n = 0; n < WN; ++n) {
            int col = bn + wc + n * 16 + rlo;
            if (col >= N) continue;
            #pragma unroll
            for (int i = 0; i < 4; ++i) {
                int row = bm + wr + m * 16 + lhi * 4 + i;
                float v = acc[m][n][i];
                if (bias) v += bias[col];
                if (act == 1)      v = gelu_exact_(v);
                else if (act == 2) v = tanhf(scale * v);
                if (resid) v += resid[(size_t)row * N + col];
                if (C)  C[(size_t)row * N + col] = v;
                if (Cb) Cb[(size_t)row * N + col] = (bf16_t)v;
            }
        }
    }
}

// ---------------------------------------------------------------------------
// flash-style MFMA attention (bf16 qkv in, bf16 out). Grid: (L/64, H, B).
// ---------------------------------------------------------------------------
__global__ __launch_bounds__(256) void attn_mfma_k(
    const bf16_t* __restrict__ qkv, const float* __restrict__ pv,
    const float* __restrict__ res_scale_p, bf16_t* __restrict__ o)
{
    constexpr int QB = 64;
    constexpr int NB = 64;

    __shared__ alignas(16) bf16_t Ks[NB][DH_];     // [key][d]
    __shared__ alignas(16) bf16_t Vt[DH_][NB];     // [d][key]
    __shared__ alignas(16) bf16_t Pl[4][16][NB];   // wave-private P tiles
    __shared__ float pvq_s[QB];
    __shared__ float pvk_s[NB];

    const int qt = blockIdx.x, h = blockIdx.y, b = blockIdx.z;
    const int tid = threadIdx.x;
    const int lane = tid & 63, w = tid >> 6;
    const int rlo = lane & 15, lhi = lane >> 4, l7 = lane & 7;
    const float rs = res_scale_p[0];

    const size_t rowbase = (size_t)(b * L_ + qt * QB);

    // Q fragments (raw bf16; 1/8 scaling applied to scores later)
    bf16x8 qf[2];
    {
        const bf16_t* qrow = qkv + (rowbase + w * 16 + rlo) * 3072 + h * DH_;
        #pragma unroll
        for (int kk = 0; kk < 2; ++kk)
            qf[kk] = *(const bf16x8*)(qrow + kk * 32 + lhi * 8);
    }
    if (tid < QB) pvq_s[tid] = pv[(rowbase + tid) * H_ + h];

    float m_r[4], l_r[4];
    f32x4 acc_o[4];
    #pragma unroll
    for (int r = 0; r < 4; ++r) { m_r[r] = -1e30f; l_r[r] = 0.f; }
    #pragma unroll
    for (int n = 0; n < 4; ++n) {
        f32x4 z = {0.f, 0.f, 0.f, 0.f};
        acc_o[n] = z;
    }

    bf16_t* pw = &Pl[w][0][0];

    for (int k0 = 0; k0 < L_; k0 += NB) {
        __syncthreads();
        // ---- stage K tile [64 key][64 d], XOR-swizzled
        #pragma unroll
        for (int i = 0; i < 2; ++i) {
            int sid = i * 256 + tid;
            int row = sid >> 3, s = sid & 7;
            bf16x8 v = *(const bf16x8*)(qkv + (size_t)(b * L_ + k0 + row) * 3072
                                        + 1024 + h * DH_ + s * 8);
            *(bf16x8*)(&Ks[row][(s ^ (row & 7)) * 8]) = v;
        }
        // ---- stage V transposed [64 d][64 key], swizzled
        {
            int col4 = (tid & 15) * 4;      // d
            int kb   = tid >> 4;            // 0..15, 4 keys each
            bf16x4 rv[4];
            #pragma unroll
            for (int j = 0; j < 4; ++j)
                rv[j] = *(const bf16x4*)(qkv + (size_t)(b * L_ + k0 + kb * 4 + j) * 3072
                                         + 2048 + h * DH_ + col4);
            #pragma unroll
            for (int jj = 0; jj < 4; ++jj) {
                int col = col4 + jj;
                bf16x4 v;
                #pragma unroll
                for (int j = 0; j < 4; ++j)
                    v[j] = rv[j][jj];
                *(bf16x4*)(&Vt[col][((kb >> 1) ^ (col & 7)) * 8 + (kb & 1) * 4]) = v;
            }
        }
        if (tid < NB) pvk_s[tid] = pv[(size_t)(b * L_ + k0 + tid) * H_ + h];
        __syncthreads();

        // ---- S = Q @ K^T
        f32x4 sacc[4];
        #pragma unroll
        for (int n = 0; n < 4; ++n) {
            f32x4 z = {0.f, 0.f, 0.f, 0.f};
            sacc[n] = z;
        }
        #pragma unroll
        for (int kk = 0; kk < 2; ++kk) {
            int soff = ((kk * 4 + lhi) ^ l7) * 8;
            bf16x8 kf[4];
            #pragma unroll
            for (int n = 0; n < 4; ++n)
                kf[n] = *(const bf16x8*)(&Ks[n * 16 + rlo][soff]);
            #pragma unroll
            for (int n = 0; n < 4; ++n)
                sacc[n] = __builtin_amdgcn_mfma_f32_16x16x32_bf16(
                    qf[kk], kf[n], sacc[n], 0, 0, 0);
        }

        // ---- scale + phase bias + tile max (C: row q = lhi*4+r, col = n*16+rlo)
        float sv[4][4];
        float tmax[4] = {-1e30f, -1e30f, -1e30f, -1e30f};
        #pragma unroll
        for (int n = 0; n < 4; ++n) {
            float pvk = pvk_s[n * 16 + rlo];
            #pragma unroll
            for (int r = 0; r < 4; ++r) {
                float dd = pvq_s[w * 16 + lhi * 4 + r] - pvk;
                float s = sacc[n][r] * 0.125f - rs * dd * dd;
                sv[n][r] = s;
                tmax[r] = fmaxf(tmax[r], s);
            }
        }
        #pragma unroll
        for (int st = 1; st < 16; st <<= 1)
            #pragma unroll
            for (int r = 0; r < 4; ++r)
                tmax[r] = fmaxf(tmax[r], __shfl_xor(tmax[r], st));

        // ---- online softmax update
        float tsum[4] = {0.f, 0.f, 0.f, 0.f};
        #pragma unroll
        for (int r = 0; r < 4; ++r) {
            float mn = fmaxf(m_r[r], tmax[r]);
            float sc = expf(m_r[r] - mn);
            m_r[r] = mn;
            l_r[r] *= sc;
            #pragma unroll
            for (int n = 0; n < 4; ++n) acc_o[n][r] *= sc;
        }
        #pragma unroll
        for (int n = 0; n < 4; ++n) {
            int key = n * 16 + rlo;
            #pragma unroll
            for (int r = 0; r < 4; ++r) {
                float p = expf(sv[n][r] - m_r[r]);
                tsum[r] += p;
                int q = lhi * 4 + r;
                pw[q * NB + (((key >> 3) ^ (q & 7)) * 8 + (key & 7))] = (bf16_t)p;
            }
        }
        #pragma unroll
        for (int st = 1; st < 16; st <<= 1)
            #pragma unroll
            for (int r = 0; r < 4; ++r)
                tsum[r] += __shfl_xor(tsum[r], st);
        #pragma unroll
        for (int r = 0; r < 4; ++r) l_r[r] += tsum[r];

        // ---- O += P @ V
        #pragma unroll
        for (int kk = 0; kk < 2; ++kk) {
            int soff = ((kk * 4 + lhi) ^ l7) * 8;
            bf16x8 pa = *(const bf16x8*)(pw + rlo * NB + (((kk * 4 + lhi) ^ (rlo & 7)) * 8));
            bf16x8 vf[4];
            #pragma unroll
            for (int n = 0; n < 4; ++n)
                vf[n] = *(const bf16x8*)(&Vt[n * 16 + rlo][soff]);
            #pragma unroll
            for (int n = 0; n < 4; ++n)
                acc_o[n] = __builtin_amdgcn_mfma_f32_16x16x32_bf16(
                    pa, vf[n], acc_o[n], 0, 0, 0);
        }
    }

    // ---- normalize and write bf16
    float inv[4];
    #pragma unroll
    for (int r = 0; r < 4; ++r) inv[r] = 1.0f / l_r[r];
    #pragma unroll
    for (int n = 0; n < 4; ++n)
        #pragma unroll
        for (int r = 0; r < 4; ++r)
            o[(rowbase + w * 16 + lhi * 4 + r) * D_ + h * DH_ + n * 16 + rlo] =
                (bf16_t)(acc_o[n][r] * inv[r]);
}

// ---------------------------------------------------------------------------
// boundary second layer: ss[t] = sigmoid(dot(h[t], w2) + b2). block per token.
// ---------------------------------------------------------------------------
__global__ __launch_bounds__(256) void bnd2_k(
    const float* __restrict__ hbuf, const float* __restrict__ w2,
    const float* __restrict__ b2, float* __restrict__ ss_out)
{
    int t = blockIdx.x, tid = threadIdx.x;
    __shared__ float red[256];
    float acc = 0.f;
    #pragma unroll
    for (int it = 0; it < 2; ++it) {
        int d = it * 256 + tid;
        acc += hbuf[(size_t)t * HID_ + d] * w2[d];
    }
    float s = block_sum_(acc, red);
    if (tid == 0) ss_out[t] = sigmoidf_(s + b2[0]);
}

// ---------------------------------------------------------------------------
// grammar/shock means over layers
// ---------------------------------------------------------------------------
__global__ __launch_bounds__(256) void means_k(
    const float* __restrict__ gs, const float* __restrict__ ss,
    float* __restrict__ gsm, float* __restrict__ ssm)
{
    int i = blockIdx.x * 256 + threadIdx.x;
    if (i < BL_ * 4) {
        float s = 0.f;
        #pragma unroll
        for (int l = 0; l < NLAYER; ++l) s += gs[(size_t)l * BL_ * 4 + i];
        gsm[i] = s * (1.0f / NLAYER);
    }
    if (i < BL_) {
        float s = 0.f;
        #pragma unroll
        for (int l = 0; l < NLAYER; ++l) s += ss[(size_t)l * BL_ + i];
        ssm[i] = s * (1.0f / NLAYER);
    }
}

// ---------------------------------------------------------------------------
// launcher
// ---------------------------------------------------------------------------
extern "C" void kernel_launch(void* const* d_in, const int* in_sizes, int n_in,
                              void* d_out, int out_size, void* d_ws, size_t ws_size,
                              hipStream_t stream) {
    const int*   ids       = (const int*)  d_in[0];
    const float* embed     = (const float*)d_in[1];
    const float* pos_enc   = (const float*)d_in[2];
    const float* rg_w      = (const float*)d_in[3];
    const float* rg_b      = (const float*)d_in[4];
    const float* qkv_w     = (const float*)d_in[5];
    const float* qkv_b     = (const float*)d_in[6];
    const float* out_w     = (const float*)d_in[7];
    const float* out_b     = (const float*)d_in[8];
    const float* ph_w      = (const float*)d_in[9];
    const float* ph_b      = (const float*)d_in[10];
    const float* res_scale = (const float*)d_in[11];
    const float* ph_scale  = (const float*)d_in[12];
    const float* ff1_w     = (const float*)d_in[13];
    const float* ff1_b     = (const float*)d_in[14];
    const float* ff2_w     = (const float*)d_in[15];
    const float* ff2_b     = (const float*)d_in[16];
    const float* n1_g      = (const float*)d_in[17];
    const float* n1_b      = (const float*)d_in[18];
    const float* n2_g      = (const float*)d_in[19];
    const float* n2_b      = (const float*)d_in[20];
    const float* bnd_w1    = (const float*)d_in[21];
    const float* bnd_b1    = (const float*)d_in[22];
    const float* bnd_w2    = (const float*)d_in[23];
    const float* bnd_b2    = (const float*)d_in[24];
    const float* fn_g      = (const float*)d_in[25];
    const float* fn_b      = (const float*)d_in[26];

    float* out = (float*)d_out;
    float* ws  = (float*)d_ws;

    // workspace layout (float slots). bf16 buffers occupy half-slots.
    const size_t M1 = 1024 * 1024;
    float*  x    = ws;                                  // [0, 2M)
    float*  xm   = ws + 2 * M1;                         // [2M, 4M)
    float*  bndh = ws + 4 * M1;                         // [4M, 5M)
    float*  pvb  = ws + 5 * M1;                         // 32K floats
    bf16_t* ainb = (bf16_t*)(ws + 5 * M1 + M1 / 4);     // 2048x1024 bf16 (1M slots)
    bf16_t* aob  = (bf16_t*)(ws + 6 * M1 + M1 / 4);     // 2048x1024 bf16
    bf16_t* xb   = (bf16_t*)(ws + 7 * M1 + M1 / 4);     // 2048x1024 bf16
    bf16_t* qkvb = (bf16_t*)(ws + 8 * M1 + M1 / 4);     // 2048x3072 bf16 (3M slots)
    bf16_t* ffhb = (bf16_t*)(ws + 11 * M1 + M1 / 4);    // 2048x4096 bf16 (4M slots)
    float*  wT   = ws + 15 * M1 + M1 / 4;               // per-layer bf16 W^T scratch (6M slots)
    bf16_t* qkvT = (bf16_t*)(wT);                       // 3072x1024
    bf16_t* outT = (bf16_t*)(wT + 1572864);             // 1024x1024
    bf16_t* ff1T = (bf16_t*)(wT + 2097152);             // 4096x1024
    bf16_t* ff2T = (bf16_t*)(wT + 4194304);             // 1024x4096
    bf16_t* bndT = (bf16_t*)(wT + 6291456);             // 512x1024 (converted once)
    bf16_t* embB = qkvb;                                // embed bf16, aliases dead bufs
                                                        // [8.25M, 23.61M) after loop

    // output offsets (floats, concatenated return order)
    const size_t o_logits = 0;
    const size_t o_x      = (size_t)BL_ * V_;
    const size_t o_gsm    = o_x + (size_t)BL_ * D_;
    const size_t o_ssm    = o_gsm + (size_t)BL_ * 4;
    const size_t o_gs     = o_ssm + (size_t)BL_;
    const size_t o_ss     = o_gs + (size_t)NLAYER * BL_ * 4;

    embed_k<<<BL_, 256, 0, stream>>>(ids, embed, pos_enc, x);

    // boundary W1 -> bf16 [512][1024], once
    tcw_k<<<512, 256, 0, stream>>>(
        bnd_w1, bndT, D_, HID_, 512,
        bnd_w1, bndT, D_, HID_, 512,
        bnd_w1, bndT, D_, HID_, 512,
        bnd_w1, bndT, D_, HID_, 512);

    const int MT = BL_ / 128;  // 16 m-tiles

    for (int i = 0; i < NLAYER; ++i) {
        // convert this layer's 4 weights to bf16 W^T (one dispatch)
        tcw_k<<<12288, 256, 0, stream>>>(
            qkv_w + (size_t)i * D_ * 3 * D_,    qkvT, D_,     3 * D_, 3072,
            out_w + (size_t)i * D_ * D_,        outT, D_,     D_,     4096,
            ff1_w + (size_t)i * D_ * 4 * D_,    ff1T, D_,     4 * D_, 8192,
            ff2_w + (size_t)i * 4 * D_ * D_,    ff2T, 4 * D_, D_,     12288);

        rg_xm_ln_k<<<BL_, 256, 0, stream>>>(
            x, rg_w + (size_t)i * D_ * 4, rg_b + (size_t)i * 4,
            n1_g + (size_t)i * D_, n1_b + (size_t)i * D_,
            ph_w + (size_t)i * D_ * H_, ph_b + (size_t)i * H_, ph_scale + i,
            xm, ainb, pvb, out + o_gs + (size_t)i * BL_ * 4);

        // QKV: 2048 x 3072 x 1024 -> qkvb (bf16)
        gemm_bf_k<128><<<MT * 24, 256, 0, stream>>>(
            ainb, qkvT, qkv_b + (size_t)i * 3 * D_, nullptr,
            nullptr, qkvb, BL_, 3 * D_, D_, MT, 4, 0, nullptr);

        dim3 ga(L_ / 64, H_, B_);
        attn_mfma_k<<<ga, 256, 0, stream>>>(qkvb, pvb, res_scale + i, aob);

        // out-proj: 2048 x 1024 x 1024 (+xm resid) -> x (f32)
        gemm_bf_k<64><<<MT * 16, 256, 0, stream>>>(
            aob, outT, out_b + (size_t)i * D_, xm,
            x, nullptr, BL_, D_, D_, MT, 4, 0, nullptr);

        ln_k<<<BL_, 256, 0, stream>>>(x, n2_g + (size_t)i * D_, n2_b + (size_t)i * D_,
                                      nullptr, ainb);

        // FF1: 2048 x 4096 x 1024, exact GELU -> ffhb (bf16)
        gemm_bf_k<128><<<MT * 32, 256, 0, stream>>>(
            ainb, ff1T, ff1_b + (size_t)i * 4 * D_, nullptr,
            nullptr, ffhb, BL_, 4 * D_, D_, MT, 4, 1, nullptr);

        // FF2: 2048 x 1024 x 4096 (+x resid) -> x (f32) and xb (bf16)
        gemm_bf_k<64><<<MT * 16, 256, 0, stream>>>(
            ffhb, ff2T, ff2_b + (size_t)i * D_, x,
            x, xb, BL_, D_, 4 * D_, MT, 4, 0, nullptr);

        // boundary-1: 2048 x 512 x 1024, tanh -> bndh (f32)
        gemm_bf_k<64><<<MT * 8, 256, 0, stream>>>(
            xb, bndT, bnd_b1, nullptr,
            bndh, nullptr, BL_, HID_, D_, MT, 4, 2, nullptr);

        bnd2_k<<<BL_, 256, 0, stream>>>(bndh, bnd_w2, bnd_b2, out + o_ss + (size_t)i * BL_);
    }

    // final LN -> f32 output tensor + bf16 logits operand
    ln_k<<<BL_, 256, 0, stream>>>(x, fn_g, fn_b, out + o_x, xb);

    // embed -> bf16 (aliases dead qkvb/ffhb/wT region)
    cvtb_k<<<4096, 256, 0, stream>>>(embed, embB, V_ * D_ / 8);

    // tied head: 2048 x 30000 x 1024
    gemm_bf_k<128><<<MT * 235, 256, 0, stream>>>(
        xb, embB, nullptr, nullptr,
        out + o_logits, nullptr, BL_, V_, D_, MT, 5, 0, nullptr);

    means_k<<<(BL_ * 4 + 255) / 256, 256, 0, stream>>>(
        out + o_gs, out + o_ss, out + o_gsm, out + o_ssm);
}

// Round 4
// 2587.258 us; speedup vs baseline: 8.0529x; 1.0277x over previous
//
#include <hip/hip_runtime.h>
#include <math.h>

// Problem constants
constexpr int NLAYER = 6;
constexpr int B_ = 2;
constexpr int L_ = 1024;
constexpr int D_ = 1024;
constexpr int H_ = 16;
constexpr int DH_ = 64;
constexpr int V_ = 30000;
constexpr int HID_ = 512;
constexpr int BL_ = B_ * L_;          // 2048 token rows

// bf16 / MFMA types
typedef __bf16 bf16_t;
typedef bf16_t bf16x8 __attribute__((ext_vector_type(8)));
typedef bf16_t bf16x4 __attribute__((ext_vector_type(4)));
typedef float  f32x4  __attribute__((ext_vector_type(4)));

// global->LDS direct staging, 16B per lane. LDS dest is wave-uniform base;
// HW writes base + lane*16. Global addr is per-lane.
#define GLOAD_LDS16(gp, lp)                                                    \
    __builtin_amdgcn_global_load_lds(                                          \
        (const __attribute__((address_space(1))) void*)(gp),                   \
        (__attribute__((address_space(3))) void*)(lp), 16, 0, 0)

// ---------------------------------------------------------------------------
// helpers (fast transcendental paths: v_exp_f32-based, ~1e-6 abs err,
// negligible vs the 0.0625 harness tolerance)
// ---------------------------------------------------------------------------
__device__ __forceinline__ float sigmoidf_(float z) { return 1.0f / (1.0f + __expf(-z)); }
__device__ __forceinline__ float tanhf_(float z) {
    float a = fabsf(z);
    float e = __expf(-2.0f * a);
    float r = (1.0f - e) / (1.0f + e);
    return copysignf(r, z);
}
__device__ __forceinline__ float gelu_exact_(float z) {
    return 0.5f * z * (1.0f + erff(z * 0.70710678118654752440f));
}

__device__ __forceinline__ bf16x8 pack8_(const float* __restrict__ src) {
    float4 f0 = *(const float4*)(src);
    float4 f1 = *(const float4*)(src + 4);
    bf16x8 v;
    v[0] = (bf16_t)f0.x; v[1] = (bf16_t)f0.y; v[2] = (bf16_t)f0.z; v[3] = (bf16_t)f0.w;
    v[4] = (bf16_t)f1.x; v[5] = (bf16_t)f1.y; v[6] = (bf16_t)f1.z; v[7] = (bf16_t)f1.w;
    return v;
}

// block-wide sum, blockDim.x == 256, `red` is shared float[256]
__device__ __forceinline__ float block_sum_(float v, float* red) {
    int tid = threadIdx.x;
    red[tid] = v; __syncthreads();
    #pragma unroll
    for (int s = 128; s > 0; s >>= 1) {
        if (tid < s) red[tid] += red[tid + s];
        __syncthreads();
    }
    float r = red[0];
    __syncthreads();
    return r;
}

// ---------------------------------------------------------------------------
// x = embed[ids]*sqrt(D) + pos_enc   (one block per token row)
// ---------------------------------------------------------------------------
__global__ __launch_bounds__(256) void embed_k(
    const int* __restrict__ ids, const float* __restrict__ emb,
    const float* __restrict__ pos, float* __restrict__ x)
{
    int t = blockIdx.x, tid = threadIdx.x;
    int id = ids[t];
    int l = t % L_;
    #pragma unroll
    for (int it = 0; it < 4; ++it) {
        int d = it * 256 + tid;
        x[(size_t)t * D_ + d] = emb[(size_t)id * D_ + d] * 32.0f + pos[(size_t)l * D_ + d];
    }
}

// ---------------------------------------------------------------------------
// weight transpose+convert: up to 4 tensors, f32 src[K][N] -> bf16 dst[N][K].
// 32x32 tiles via LDS; vectorized bf16x4 writes (8B/lane).
// ---------------------------------------------------------------------------
__global__ __launch_bounds__(256) void tcw_k(
    const float* s0, bf16_t* d0, int K0, int N0, int c0,
    const float* s1, bf16_t* d1, int K1, int N1, int c1,
    const float* s2, bf16_t* d2, int K2, int N2, int c2,
    const float* s3, bf16_t* d3, int K3, int N3, int c3)
{
    __shared__ float t32[32][33];
    int bid = blockIdx.x;
    const float* s; bf16_t* d; int K, N, base;
    if (bid < c0)      { s = s0; d = d0; K = K0; N = N0; base = 0; }
    else if (bid < c1) { s = s1; d = d1; K = K1; N = N1; base = c0; }
    else if (bid < c2) { s = s2; d = d2; K = K2; N = N2; base = c1; }
    else               { s = s3; d = d3; K = K3; N = N3; base = c2; }
    int tt = bid - base;
    int KT = K >> 5;
    int kt = tt % KT, nt = tt / KT;
    int tid = threadIdx.x, cx = tid & 31, ry = tid >> 5;
    #pragma unroll
    for (int j = 0; j < 4; ++j)
        t32[ry + 8 * j][cx] = s[(size_t)(kt * 32 + ry + 8 * j) * N + nt * 32 + cx];
    __syncthreads();
    int r = tid >> 3, c4 = (tid & 7) * 4;
    bf16x4 v;
    #pragma unroll
    for (int j = 0; j < 4; ++j) v[j] = (bf16_t)t32[c4 + j][r];
    *(bf16x4*)(d + (size_t)(nt * 32 + r) * K + kt * 32 + c4) = v;
}

// ---------------------------------------------------------------------------
// straight f32 -> bf16 convert (8 elems/thread, grid-stride)
// ---------------------------------------------------------------------------
__global__ __launch_bounds__(256) void cvtb_k(
    const float* __restrict__ s, bf16_t* __restrict__ d, int n8)
{
    for (int i = blockIdx.x * 256 + threadIdx.x; i < n8; i += gridDim.x * 256)
        *(bf16x8*)(d + (size_t)i * 8) = pack8_(s + (size_t)i * 8);
}

// ---------------------------------------------------------------------------
// fused: rg = sigmoid(x@rg_w + rg_b); store gs; xm = x*(1+0.1*mean(rg));
//        a_in = LayerNorm(xm) -> ainb (bf16);
//        pv = tanh(ps * (a_in @ ph_w + ph_b)) -> pvb.  One block per token.
// ---------------------------------------------------------------------------
__global__ __launch_bounds__(256) void rg_xm_ln_k(
    const float* __restrict__ x, const float* __restrict__ rgw,
    const float* __restrict__ rgb, const float* __restrict__ g,
    const float* __restrict__ b, const float* __restrict__ phw,
    const float* __restrict__ phb, const float* __restrict__ ps_p,
    float* __restrict__ xm, bf16_t* __restrict__ ainb,
    float* __restrict__ pvb, float* __restrict__ gs_out)
{
    int t = blockIdx.x, tid = threadIdx.x;
    __shared__ float xr[D_];
    __shared__ float red[256];
    __shared__ float rgsh[4];

    #pragma unroll
    for (int it = 0; it < 4; ++it) {
        int d = it * 256 + tid;
        xr[d] = x[(size_t)t * D_ + d];
    }
    __syncthreads();

    float a0 = 0.f, a1 = 0.f, a2 = 0.f, a3 = 0.f;
    #pragma unroll
    for (int it = 0; it < 4; ++it) {
        int d = it * 256 + tid;
        float xv = xr[d];
        float4 w = *(const float4*)(rgw + (size_t)d * 4);
        a0 += xv * w.x; a1 += xv * w.y; a2 += xv * w.z; a3 += xv * w.w;
    }
    float s0 = block_sum_(a0, red);
    float s1 = block_sum_(a1, red);
    float s2 = block_sum_(a2, red);
    float s3 = block_sum_(a3, red);
    if (tid == 0) {
        float r0 = sigmoidf_(s0 + rgb[0]);
        float r1 = sigmoidf_(s1 + rgb[1]);
        float r2 = sigmoidf_(s2 + rgb[2]);
        float r3 = sigmoidf_(s3 + rgb[3]);
        rgsh[0] = r0; rgsh[1] = r1; rgsh[2] = r2; rgsh[3] = r3;
        gs_out[(size_t)t * 4 + 0] = r0;
        gs_out[(size_t)t * 4 + 1] = r1;
        gs_out[(size_t)t * 4 + 2] = r2;
        gs_out[(size_t)t * 4 + 3] = r3;
    }
    __syncthreads();
    float factor = 1.0f + 0.025f * (rgsh[0] + rgsh[1] + rgsh[2] + rgsh[3]);

    float sm = 0.f, sq = 0.f;
    float vals[4];
    #pragma unroll
    for (int it = 0; it < 4; ++it) {
        int d = it * 256 + tid;
        float v = xr[d] * factor;
        vals[it] = v;
        xm[(size_t)t * D_ + d] = v;
        sm += v; sq += v * v;
    }
    float mean = block_sum_(sm, red) * (1.0f / D_);
    float msq  = block_sum_(sq, red) * (1.0f / D_);
    float rstd = rsqrtf(msq - mean * mean + 1e-5f);
    #pragma unroll
    for (int it = 0; it < 4; ++it) {
        int d = it * 256 + tid;
        float a = (vals[it] - mean) * rstd * g[d] + b[d];
        ainb[(size_t)t * D_ + d] = (bf16_t)a;
        xr[d] = a;                      // keep LN output for phase GEMV
    }
    __syncthreads();

    // phase GEMV: col c = tid&15, k-chunk grp = tid>>4 (64 k each)
    {
        int c = tid & 15, grp = tid >> 4;
        float acc = 0.f;
        int k0 = grp * 64;
        #pragma unroll
        for (int kk = 0; kk < 64; ++kk)
            acc += xr[k0 + kk] * phw[(size_t)(k0 + kk) * H_ + c];
        red[tid] = acc;
        __syncthreads();
        if (tid < 16) {
            float s = 0.f;
            #pragma unroll
            for (int gg = 0; gg < 16; ++gg) s += red[gg * 16 + tid];
            pvb[(size_t)t * H_ + tid] = tanhf_(ps_p[0] * (s + phb[tid]));
        }
    }
}

// ---------------------------------------------------------------------------
// LayerNorm over rows of D_; writes f32 (optional) and/or bf16 (optional).
// ---------------------------------------------------------------------------
__global__ __launch_bounds__(256) void ln_k(
    const float* __restrict__ in, const float* __restrict__ g,
    const float* __restrict__ b, float* __restrict__ outp,
    bf16_t* __restrict__ outb)
{
    int t = blockIdx.x, tid = threadIdx.x;
    __shared__ float red[256];
    float s1 = 0.f, s2 = 0.f;
    float vals[4];
    #pragma unroll
    for (int it = 0; it < 4; ++it) {
        int d = it * 256 + tid;
        float v = in[(size_t)t * D_ + d];
        vals[it] = v; s1 += v; s2 += v * v;
    }
    float mean = block_sum_(s1, red) * (1.0f / D_);
    float msq  = block_sum_(s2, red) * (1.0f / D_);
    float rstd = rsqrtf(msq - mean * mean + 1e-5f);
    #pragma unroll
    for (int it = 0; it < 4; ++it) {
        int d = it * 256 + tid;
        float v = (vals[it] - mean) * rstd * g[d] + b[d];
        if (outp) outp[(size_t)t * D_ + d] = v;
        if (outb) outb[(size_t)t * D_ + d] = (bf16_t)v;
    }
}

// ---------------------------------------------------------------------------
// bf16 MFMA GEMM (m97 structure): C = act(A @ B^T + bias) (+resid)
//   A: bf16 [M][K] row-major; Bm: bf16 [N][K] row-major (k-contiguous).
//   global_load_lds dwordx4 staging into linear LDS; ds_read_b128 fragments.
// Tile 128xBN, BK=64; 256 threads = 4 waves; wave tile 64 x (BN/2).
// C: optional f32 out (+bias/act/resid), Cb: optional bf16 out.
// ---------------------------------------------------------------------------
template<int BN>
__global__ __launch_bounds__(256) void gemm_bf_k(
    const bf16_t* __restrict__ A, const bf16_t* __restrict__ Bm,
    const float* __restrict__ bias, const float* __restrict__ resid,
    float* __restrict__ C, bf16_t* __restrict__ Cb,
    int M, int N, int K, int MT, int GW,
    int act, const float* __restrict__ scale_ptr)
{
    constexpr int BM = 128;
    constexpr int BK = 64;
    constexpr int WN = BN / 32;      // n-frags per wave

    __shared__ alignas(16) bf16_t As[BM][BK];
    __shared__ alignas(16) bf16_t Bs[BN][BK];

    const int tid  = threadIdx.x;
    const int lane = tid & 63;
    const int w    = tid >> 6;

    // grouped block swizzle: m-fastest within an n-group (weight tile L2-resident)
    int per = MT * GW;
    int grp = blockIdx.x / per;
    int r   = blockIdx.x % per;
    int mi  = r % MT;
    int ni  = grp * GW + r / MT;
    const int bm = mi * BM;
    const int bn = ni * BN;

    const int wr = (w & 1) * 64;
    const int wc = (w >> 1) * (BN / 2);
    const int rlo = lane & 15, lhi = lane >> 4;
    const int srow = lane >> 3;          // staging: row within 8-row slab
    const int scol = (lane & 7) * 8;     // staging: elem offset (16B chunk)

    f32x4 acc[4][WN];
    #pragma unroll
    for (int m = 0; m < 4; ++m)
        #pragma unroll
        for (int n = 0; n < WN; ++n) {
            f32x4 z = {0.f, 0.f, 0.f, 0.f};
            acc[m][n] = z;
        }

    for (int kt = 0; kt < K; kt += BK) {
        __syncthreads();
        // ---- stage A: 16 slabs of 8 rows, 4 per wave
        #pragma unroll
        for (int i = 0; i < 4; ++i) {
            int is = w * 4 + i;
            const bf16_t* gp = A + (size_t)(bm + is * 8 + srow) * K + kt + scol;
            GLOAD_LDS16(gp, &As[is * 8][0]);
        }
        // ---- stage B: BN/8 slabs, row-clamped for N edge
        #pragma unroll
        for (int i = 0; i < BN / 32; ++i) {
            int is = w * (BN / 32) + i;
            int row = bn + is * 8 + srow;
            if (row > N - 1) row = N - 1;
            const bf16_t* gp = Bm + (size_t)row * K + kt + scol;
            GLOAD_LDS16(gp, &Bs[is * 8][0]);
        }
        __syncthreads();

        // ---- compute: 2 k-halves of 32
        #pragma unroll
        for (int h2 = 0; h2 < 2; ++h2) {
            int ko = h2 * 32 + lhi * 8;
            bf16x8 af[4], bfr[WN];
            #pragma unroll
            for (int m = 0; m < 4; ++m)
                af[m] = *(const bf16x8*)(&As[wr + m * 16 + rlo][ko]);
            #pragma unroll
            for (int n = 0; n < WN; ++n)
                bfr[n] = *(const bf16x8*)(&Bs[wc + n * 16 + rlo][ko]);
            #pragma unroll
            for (int m = 0; m < 4; ++m)
                #pragma unroll
                for (int n = 0; n < WN; ++n)
                    acc[m][n] = __builtin_amdgcn_mfma_f32_16x16x32_bf16(
                        af[m], bfr[n], acc[m][n], 0, 0, 0);
        }
    }

    // ---- epilogue: C/D layout col = lane&15, row = (lane>>4)*4 + reg
    float scale = scale_ptr ? scale_ptr[0] : 1.0f;
    #pragma unroll
    for (int m = 0; m < 4; ++m) {
        #pragma unroll
        for (int n = 0; n < WN; ++n) {
            int col = bn + wc + n * 16 + rlo;
            if (col >= N) continue;
            #pragma unroll
            for (int i = 0; i < 4; ++i) {
                int row = bm + wr + m * 16 + lhi * 4 + i;
                float v = acc[m][n][i];
                if (bias) v += bias[col];
                if (act == 1)      v = gelu_exact_(v);
                else if (act == 2) v = tanhf_(scale * v);
                if (resid) v += resid[(size_t)row * N + col];
                if (C)  C[(size_t)row * N + col] = v;
                if (Cb) Cb[(size_t)row * N + col] = (bf16_t)v;
            }
        }
    }
}

// ---------------------------------------------------------------------------
// flash-style MFMA attention (bf16 qkv in, bf16 out). Grid: (L/64, H, B).
// Fast __expf softmax; s_setprio around MFMA clusters (T5).
// ---------------------------------------------------------------------------
__global__ __launch_bounds__(256) void attn_mfma_k(
    const bf16_t* __restrict__ qkv, const float* __restrict__ pv,
    const float* __restrict__ res_scale_p, bf16_t* __restrict__ o)
{
    constexpr int QB = 64;
    constexpr int NB = 64;

    __shared__ alignas(16) bf16_t Ks[NB][DH_];     // [key][d]
    __shared__ alignas(16) bf16_t Vt[DH_][NB];     // [d][key]
    __shared__ alignas(16) bf16_t Pl[4][16][NB];   // wave-private P tiles
    __shared__ float pvq_s[QB];
    __shared__ float pvk_s[NB];

    const int qt = blockIdx.x, h = blockIdx.y, b = blockIdx.z;
    const int tid = threadIdx.x;
    const int lane = tid & 63, w = tid >> 6;
    const int rlo = lane & 15, lhi = lane >> 4, l7 = lane & 7;
    const float rs = res_scale_p[0];

    const size_t rowbase = (size_t)(b * L_ + qt * QB);

    // Q fragments (raw bf16; 1/8 scaling applied to scores later)
    bf16x8 qf[2];
    {
        const bf16_t* qrow = qkv + (rowbase + w * 16 + rlo) * 3072 + h * DH_;
        #pragma unroll
        for (int kk = 0; kk < 2; ++kk)
            qf[kk] = *(const bf16x8*)(qrow + kk * 32 + lhi * 8);
    }
    if (tid < QB) pvq_s[tid] = pv[(rowbase + tid) * H_ + h];
    __syncthreads();
    float pvq_r[4];
    #pragma unroll
    for (int r = 0; r < 4; ++r) pvq_r[r] = pvq_s[w * 16 + lhi * 4 + r];

    float m_r[4], l_r[4];
    f32x4 acc_o[4];
    #pragma unroll
    for (int r = 0; r < 4; ++r) { m_r[r] = -1e30f; l_r[r] = 0.f; }
    #pragma unroll
    for (int n = 0; n < 4; ++n) {
        f32x4 z = {0.f, 0.f, 0.f, 0.f};
        acc_o[n] = z;
    }

    bf16_t* pw = &Pl[w][0][0];

    for (int k0 = 0; k0 < L_; k0 += NB) {
        __syncthreads();
        // ---- stage K tile [64 key][64 d], XOR-swizzled
        #pragma unroll
        for (int i = 0; i < 2; ++i) {
            int sid = i * 256 + tid;
            int row = sid >> 3, s = sid & 7;
            bf16x8 v = *(const bf16x8*)(qkv + (size_t)(b * L_ + k0 + row) * 3072
                                        + 1024 + h * DH_ + s * 8);
            *(bf16x8*)(&Ks[row][(s ^ (row & 7)) * 8]) = v;
        }
        // ---- stage V transposed [64 d][64 key], swizzled
        {
            int col4 = (tid & 15) * 4;      // d
            int kb   = tid >> 4;            // 0..15, 4 keys each
            bf16x4 rv[4];
            #pragma unroll
            for (int j = 0; j < 4; ++j)
                rv[j] = *(const bf16x4*)(qkv + (size_t)(b * L_ + k0 + kb * 4 + j) * 3072
                                         + 2048 + h * DH_ + col4);
            #pragma unroll
            for (int jj = 0; jj < 4; ++jj) {
                int col = col4 + jj;
                bf16x4 v;
                #pragma unroll
                for (int j = 0; j < 4; ++j)
                    v[j] = rv[j][jj];
                *(bf16x4*)(&Vt[col][((kb >> 1) ^ (col & 7)) * 8 + (kb & 1) * 4]) = v;
            }
        }
        if (tid < NB) pvk_s[tid] = pv[(size_t)(b * L_ + k0 + tid) * H_ + h];
        __syncthreads();

        // ---- S = Q @ K^T
        f32x4 sacc[4];
        #pragma unroll
        for (int n = 0; n < 4; ++n) {
            f32x4 z = {0.f, 0.f, 0.f, 0.f};
            sacc[n] = z;
        }
        __builtin_amdgcn_s_setprio(1);
        #pragma unroll
        for (int kk = 0; kk < 2; ++kk) {
            int soff = ((kk * 4 + lhi) ^ l7) * 8;
            bf16x8 kf[4];
            #pragma unroll
            for (int n = 0; n < 4; ++n)
                kf[n] = *(const bf16x8*)(&Ks[n * 16 + rlo][soff]);
            #pragma unroll
            for (int n = 0; n < 4; ++n)
                sacc[n] = __builtin_amdgcn_mfma_f32_16x16x32_bf16(
                    qf[kk], kf[n], sacc[n], 0, 0, 0);
        }
        __builtin_amdgcn_s_setprio(0);

        // ---- scale + phase bias + tile max (C: row q = lhi*4+r, col = n*16+rlo)
        float sv[4][4];
        float tmax[4] = {-1e30f, -1e30f, -1e30f, -1e30f};
        #pragma unroll
        for (int n = 0; n < 4; ++n) {
            float pvk = pvk_s[n * 16 + rlo];
            #pragma unroll
            for (int r = 0; r < 4; ++r) {
                float dd = pvq_r[r] - pvk;
                float s = sacc[n][r] * 0.125f - rs * dd * dd;
                sv[n][r] = s;
                tmax[r] = fmaxf(tmax[r], s);
            }
        }
        #pragma unroll
        for (int st = 1; st < 16; st <<= 1)
            #pragma unroll
            for (int r = 0; r < 4; ++r)
                tmax[r] = fmaxf(tmax[r], __shfl_xor(tmax[r], st));

        // ---- online softmax update (fast exp)
        float tsum[4] = {0.f, 0.f, 0.f, 0.f};
        #pragma unroll
        for (int r = 0; r < 4; ++r) {
            float mn = fmaxf(m_r[r], tmax[r]);
            float sc = __expf(m_r[r] - mn);
            m_r[r] = mn;
            l_r[r] *= sc;
            #pragma unroll
            for (int n = 0; n < 4; ++n) acc_o[n][r] *= sc;
        }
        #pragma unroll
        for (int n = 0; n < 4; ++n) {
            int key = n * 16 + rlo;
            #pragma unroll
            for (int r = 0; r < 4; ++r) {
                float p = __expf(sv[n][r] - m_r[r]);
                tsum[r] += p;
                int q = lhi * 4 + r;
                pw[q * NB + (((key >> 3) ^ (q & 7)) * 8 + (key & 7))] = (bf16_t)p;
            }
        }
        #pragma unroll
        for (int st = 1; st < 16; st <<= 1)
            #pragma unroll
            for (int r = 0; r < 4; ++r)
                tsum[r] += __shfl_xor(tsum[r], st);
        #pragma unroll
        for (int r = 0; r < 4; ++r) l_r[r] += tsum[r];

        // ---- O += P @ V
        __builtin_amdgcn_s_setprio(1);
        #pragma unroll
        for (int kk = 0; kk < 2; ++kk) {
            int soff = ((kk * 4 + lhi) ^ l7) * 8;
            bf16x8 pa = *(const bf16x8*)(pw + rlo * NB + (((kk * 4 + lhi) ^ (rlo & 7)) * 8));
            bf16x8 vf[4];
            #pragma unroll
            for (int n = 0; n < 4; ++n)
                vf[n] = *(const bf16x8*)(&Vt[n * 16 + rlo][soff]);
            #pragma unroll
            for (int n = 0; n < 4; ++n)
                acc_o[n] = __builtin_amdgcn_mfma_f32_16x16x32_bf16(
                    pa, vf[n], acc_o[n], 0, 0, 0);
        }
        __builtin_amdgcn_s_setprio(0);
    }

    // ---- normalize and write bf16
    float inv[4];
    #pragma unroll
    for (int r = 0; r < 4; ++r) inv[r] = 1.0f / l_r[r];
    #pragma unroll
    for (int n = 0; n < 4; ++n)
        #pragma unroll
        for (int r = 0; r < 4; ++r)
            o[(rowbase + w * 16 + lhi * 4 + r) * D_ + h * DH_ + n * 16 + rlo] =
                (bf16_t)(acc_o[n][r] * inv[r]);
}

// ---------------------------------------------------------------------------
// boundary second layer: ss[t] = sigmoid(dot(h[t], w2) + b2). block per token.
// ---------------------------------------------------------------------------
__global__ __launch_bounds__(256) void bnd2_k(
    const float* __restrict__ hbuf, const float* __restrict__ w2,
    const float* __restrict__ b2, float* __restrict__ ss_out)
{
    int t = blockIdx.x, tid = threadIdx.x;
    __shared__ float red[256];
    float acc = 0.f;
    #pragma unroll
    for (int it = 0; it < 2; ++it) {
        int d = it * 256 + tid;
        acc += hbuf[(size_t)t * HID_ + d] * w2[d];
    }
    float s = block_sum_(acc, red);
    if (tid == 0) ss_out[t] = sigmoidf_(s + b2[0]);
}

// ---------------------------------------------------------------------------
// grammar/shock means over layers
// ---------------------------------------------------------------------------
__global__ __launch_bounds__(256) void means_k(
    const float* __restrict__ gs, const float* __restrict__ ss,
    float* __restrict__ gsm, float* __restrict__ ssm)
{
    int i = blockIdx.x * 256 + threadIdx.x;
    if (i < BL_ * 4) {
        float s = 0.f;
        #pragma unroll
        for (int l = 0; l < NLAYER; ++l) s += gs[(size_t)l * BL_ * 4 + i];
        gsm[i] = s * (1.0f / NLAYER);
    }
    if (i < BL_) {
        float s = 0.f;
        #pragma unroll
        for (int l = 0; l < NLAYER; ++l) s += ss[(size_t)l * BL_ + i];
        ssm[i] = s * (1.0f / NLAYER);
    }
}

// ---------------------------------------------------------------------------
// launcher
// ---------------------------------------------------------------------------
extern "C" void kernel_launch(void* const* d_in, const int* in_sizes, int n_in,
                              void* d_out, int out_size, void* d_ws, size_t ws_size,
                              hipStream_t stream) {
    const int*   ids       = (const int*)  d_in[0];
    const float* embed     = (const float*)d_in[1];
    const float* pos_enc   = (const float*)d_in[2];
    const float* rg_w      = (const float*)d_in[3];
    const float* rg_b      = (const float*)d_in[4];
    const float* qkv_w     = (const float*)d_in[5];
    const float* qkv_b     = (const float*)d_in[6];
    const float* out_w     = (const float*)d_in[7];
    const float* out_b     = (const float*)d_in[8];
    const float* ph_w      = (const float*)d_in[9];
    const float* ph_b      = (const float*)d_in[10];
    const float* res_scale = (const float*)d_in[11];
    const float* ph_scale  = (const float*)d_in[12];
    const float* ff1_w     = (const float*)d_in[13];
    const float* ff1_b     = (const float*)d_in[14];
    const float* ff2_w     = (const float*)d_in[15];
    const float* ff2_b     = (const float*)d_in[16];
    const float* n1_g      = (const float*)d_in[17];
    const float* n1_b      = (const float*)d_in[18];
    const float* n2_g      = (const float*)d_in[19];
    const float* n2_b      = (const float*)d_in[20];
    const float* bnd_w1    = (const float*)d_in[21];
    const float* bnd_b1    = (const float*)d_in[22];
    const float* bnd_w2    = (const float*)d_in[23];
    const float* bnd_b2    = (const float*)d_in[24];
    const float* fn_g      = (const float*)d_in[25];
    const float* fn_b      = (const float*)d_in[26];

    float* out = (float*)d_out;
    float* ws  = (float*)d_ws;

    // workspace layout (float slots). bf16 buffers occupy half-slots.
    const size_t M1 = 1024 * 1024;
    float*  x    = ws;                                  // [0, 2M)
    float*  xm   = ws + 2 * M1;                         // [2M, 4M)
    float*  bndh = ws + 4 * M1;                         // [4M, 5M)
    float*  pvb  = ws + 5 * M1;                         // 32K floats
    bf16_t* ainb = (bf16_t*)(ws + 5 * M1 + M1 / 4);     // 2048x1024 bf16 (1M slots)
    bf16_t* aob  = (bf16_t*)(ws + 6 * M1 + M1 / 4);     // 2048x1024 bf16
    bf16_t* xb   = (bf16_t*)(ws + 7 * M1 + M1 / 4);     // 2048x1024 bf16
    bf16_t* qkvb = (bf16_t*)(ws + 8 * M1 + M1 / 4);     // 2048x3072 bf16 (3M slots)
    bf16_t* ffhb = (bf16_t*)(ws + 11 * M1 + M1 / 4);    // 2048x4096 bf16 (4M slots)
    float*  wT   = ws + 15 * M1 + M1 / 4;               // per-layer bf16 W^T scratch (6M slots)
    bf16_t* qkvT = (bf16_t*)(wT);                       // 3072x1024
    bf16_t* outT = (bf16_t*)(wT + 1572864);             // 1024x1024
    bf16_t* ff1T = (bf16_t*)(wT + 2097152);             // 4096x1024
    bf16_t* ff2T = (bf16_t*)(wT + 4194304);             // 1024x4096
    bf16_t* bndT = (bf16_t*)(wT + 6291456);             // 512x1024 (converted once)
    bf16_t* embB = qkvb;                                // embed bf16, aliases dead bufs

    // output offsets (floats, concatenated return order)
    const size_t o_logits = 0;
    const size_t o_x      = (size_t)BL_ * V_;
    const size_t o_gsm    = o_x + (size_t)BL_ * D_;
    const size_t o_ssm    = o_gsm + (size_t)BL_ * 4;
    const size_t o_gs     = o_ssm + (size_t)BL_;
    const size_t o_ss     = o_gs + (size_t)NLAYER * BL_ * 4;

    embed_k<<<BL_, 256, 0, stream>>>(ids, embed, pos_enc, x);

    // boundary W1 -> bf16 [512][1024], once
    tcw_k<<<512, 256, 0, stream>>>(
        bnd_w1, bndT, D_, HID_, 512,
        bnd_w1, bndT, D_, HID_, 512,
        bnd_w1, bndT, D_, HID_, 512,
        bnd_w1, bndT, D_, HID_, 512);

    const int MT = BL_ / 128;  // 16 m-tiles

    for (int i = 0; i < NLAYER; ++i) {
        // convert this layer's 4 weights to bf16 W^T (one dispatch)
        tcw_k<<<12288, 256, 0, stream>>>(
            qkv_w + (size_t)i * D_ * 3 * D_,    qkvT, D_,     3 * D_, 3072,
            out_w + (size_t)i * D_ * D_,        outT, D_,     D_,     4096,
            ff1_w + (size_t)i * D_ * 4 * D_,    ff1T, D_,     4 * D_, 8192,
            ff2_w + (size_t)i * 4 * D_ * D_,    ff2T, 4 * D_, D_,     12288);

        rg_xm_ln_k<<<BL_, 256, 0, stream>>>(
            x, rg_w + (size_t)i * D_ * 4, rg_b + (size_t)i * 4,
            n1_g + (size_t)i * D_, n1_b + (size_t)i * D_,
            ph_w + (size_t)i * D_ * H_, ph_b + (size_t)i * H_, ph_scale + i,
            xm, ainb, pvb, out + o_gs + (size_t)i * BL_ * 4);

        // QKV: 2048 x 3072 x 1024 -> qkvb (bf16)
        gemm_bf_k<128><<<MT * 24, 256, 0, stream>>>(
            ainb, qkvT, qkv_b + (size_t)i * 3 * D_, nullptr,
            nullptr, qkvb, BL_, 3 * D_, D_, MT, 4, 0, nullptr);

        dim3 ga(L_ / 64, H_, B_);
        attn_mfma_k<<<ga, 256, 0, stream>>>(qkvb, pvb, res_scale + i, aob);

        // out-proj: 2048 x 1024 x 1024 (+xm resid) -> x (f32)
        gemm_bf_k<64><<<MT * 16, 256, 0, stream>>>(
            aob, outT, out_b + (size_t)i * D_, xm,
            x, nullptr, BL_, D_, D_, MT, 4, 0, nullptr);

        ln_k<<<BL_, 256, 0, stream>>>(x, n2_g + (size_t)i * D_, n2_b + (size_t)i * D_,
                                      nullptr, ainb);

        // FF1: 2048 x 4096 x 1024, exact GELU -> ffhb (bf16)
        gemm_bf_k<128><<<MT * 32, 256, 0, stream>>>(
            ainb, ff1T, ff1_b + (size_t)i * 4 * D_, nullptr,
            nullptr, ffhb, BL_, 4 * D_, D_, MT, 4, 1, nullptr);

        // FF2: 2048 x 1024 x 4096 (+x resid) -> x (f32) and xb (bf16)
        gemm_bf_k<64><<<MT * 16, 256, 0, stream>>>(
            ffhb, ff2T, ff2_b + (size_t)i * D_, x,
            x, xb, BL_, D_, 4 * D_, MT, 4, 0, nullptr);

        // boundary-1: 2048 x 512 x 1024, tanh -> bndh (f32)
        gemm_bf_k<64><<<MT * 8, 256, 0, stream>>>(
            xb, bndT, bnd_b1, nullptr,
            bndh, nullptr, BL_, HID_, D_, MT, 4, 2, nullptr);

        bnd2_k<<<BL_, 256, 0, stream>>>(bndh, bnd_w2, bnd_b2, out + o_ss + (size_t)i * BL_);
    }

    // final LN -> f32 output tensor + bf16 logits operand
    ln_k<<<BL_, 256, 0, stream>>>(x, fn_g, fn_b, out + o_x, xb);

    // embed -> bf16 (aliases dead qkvb/ffhb/wT region)
    cvtb_k<<<4096, 256, 0, stream>>>(embed, embB, V_ * D_ / 8);

    // tied head: 2048 x 30000 x 1024
    gemm_bf_k<128><<<MT * 235, 256, 0, stream>>>(
        xb, embB, nullptr, nullptr,
        out + o_logits, nullptr, BL_, V_, D_, MT, 5, 0, nullptr);

    means_k<<<(BL_ * 4 + 255) / 256, 256, 0, stream>>>(
        out + o_gs, out + o_ss, out + o_gsm, out + o_ssm);
}

// Round 5
// 2485.039 us; speedup vs baseline: 8.3841x; 1.0411x over previous
//
#include <hip/hip_runtime.h>
#include <math.h>

// Problem constants
constexpr int NLAYER = 6;
constexpr int B_ = 2;
constexpr int L_ = 1024;
constexpr int D_ = 1024;
constexpr int H_ = 16;
constexpr int DH_ = 64;
constexpr int V_ = 30000;
constexpr int HID_ = 512;
constexpr int BL_ = B_ * L_;          // 2048 token rows

// bf16 / MFMA types
typedef __bf16 bf16_t;
typedef bf16_t bf16x8 __attribute__((ext_vector_type(8)));
typedef bf16_t bf16x4 __attribute__((ext_vector_type(4)));
typedef float  f32x4  __attribute__((ext_vector_type(4)));

// global->LDS direct staging, 16B per lane. LDS dest is wave-uniform base;
// HW writes base + lane*16. Global addr is per-lane.
#define GLOAD_LDS16(gp, lp)                                                    \
    __builtin_amdgcn_global_load_lds(                                          \
        (const __attribute__((address_space(1))) void*)(gp),                   \
        (__attribute__((address_space(3))) void*)(lp), 16, 0, 0)

// ---------------------------------------------------------------------------
// helpers (fast transcendental paths: v_exp_f32-based, ~1e-6 abs err,
// negligible vs the 0.0625 harness tolerance)
// ---------------------------------------------------------------------------
__device__ __forceinline__ float sigmoidf_(float z) { return 1.0f / (1.0f + __expf(-z)); }
__device__ __forceinline__ float tanhf_(float z) {
    float a = fabsf(z);
    float e = __expf(-2.0f * a);
    float r = (1.0f - e) / (1.0f + e);
    return copysignf(r, z);
}
__device__ __forceinline__ float gelu_exact_(float z) {
    return 0.5f * z * (1.0f + erff(z * 0.70710678118654752440f));
}

__device__ __forceinline__ bf16x8 pack8_(const float* __restrict__ src) {
    float4 f0 = *(const float4*)(src);
    float4 f1 = *(const float4*)(src + 4);
    bf16x8 v;
    v[0] = (bf16_t)f0.x; v[1] = (bf16_t)f0.y; v[2] = (bf16_t)f0.z; v[3] = (bf16_t)f0.w;
    v[4] = (bf16_t)f1.x; v[5] = (bf16_t)f1.y; v[6] = (bf16_t)f1.z; v[7] = (bf16_t)f1.w;
    return v;
}

// block-wide sum, blockDim.x == 256, `red` is shared float[256]
__device__ __forceinline__ float block_sum_(float v, float* red) {
    int tid = threadIdx.x;
    red[tid] = v; __syncthreads();
    #pragma unroll
    for (int s = 128; s > 0; s >>= 1) {
        if (tid < s) red[tid] += red[tid + s];
        __syncthreads();
    }
    float r = red[0];
    __syncthreads();
    return r;
}

// ---------------------------------------------------------------------------
// x = embed[ids]*sqrt(D) + pos_enc   (one block per token row)
// ---------------------------------------------------------------------------
__global__ __launch_bounds__(256) void embed_k(
    const int* __restrict__ ids, const float* __restrict__ emb,
    const float* __restrict__ pos, float* __restrict__ x)
{
    int t = blockIdx.x, tid = threadIdx.x;
    int id = ids[t];
    int l = t % L_;
    #pragma unroll
    for (int it = 0; it < 4; ++it) {
        int d = it * 256 + tid;
        x[(size_t)t * D_ + d] = emb[(size_t)id * D_ + d] * 32.0f + pos[(size_t)l * D_ + d];
    }
}

// ---------------------------------------------------------------------------
// weight transpose+convert: up to 4 tensors, f32 src[K][N] -> bf16 dst[N][K].
// 32x32 tiles via LDS; vectorized bf16x4 writes (8B/lane).
// ---------------------------------------------------------------------------
__global__ __launch_bounds__(256) void tcw_k(
    const float* s0, bf16_t* d0, int K0, int N0, int c0,
    const float* s1, bf16_t* d1, int K1, int N1, int c1,
    const float* s2, bf16_t* d2, int K2, int N2, int c2,
    const float* s3, bf16_t* d3, int K3, int N3, int c3)
{
    __shared__ float t32[32][33];
    int bid = blockIdx.x;
    const float* s; bf16_t* d; int K, N, base;
    if (bid < c0)      { s = s0; d = d0; K = K0; N = N0; base = 0; }
    else if (bid < c1) { s = s1; d = d1; K = K1; N = N1; base = c0; }
    else if (bid < c2) { s = s2; d = d2; K = K2; N = N2; base = c1; }
    else               { s = s3; d = d3; K = K3; N = N3; base = c2; }
    int tt = bid - base;
    int KT = K >> 5;
    int kt = tt % KT, nt = tt / KT;
    int tid = threadIdx.x, cx = tid & 31, ry = tid >> 5;
    #pragma unroll
    for (int j = 0; j < 4; ++j)
        t32[ry + 8 * j][cx] = s[(size_t)(kt * 32 + ry + 8 * j) * N + nt * 32 + cx];
    __syncthreads();
    int r = tid >> 3, c4 = (tid & 7) * 4;
    bf16x4 v;
    #pragma unroll
    for (int j = 0; j < 4; ++j) v[j] = (bf16_t)t32[c4 + j][r];
    *(bf16x4*)(d + (size_t)(nt * 32 + r) * K + kt * 32 + c4) = v;
}

// ---------------------------------------------------------------------------
// straight f32 -> bf16 convert (8 elems/thread, grid-stride)
// ---------------------------------------------------------------------------
__global__ __launch_bounds__(256) void cvtb_k(
    const float* __restrict__ s, bf16_t* __restrict__ d, int n8)
{
    for (int i = blockIdx.x * 256 + threadIdx.x; i < n8; i += gridDim.x * 256)
        *(bf16x8*)(d + (size_t)i * 8) = pack8_(s + (size_t)i * 8);
}

// ---------------------------------------------------------------------------
// fused: rg = sigmoid(x@rg_w + rg_b); store gs; xm = x*(1+0.1*mean(rg));
//        a_in = LayerNorm(xm) -> ainb (bf16);
//        pv = tanh(ps * (a_in @ ph_w + ph_b)) -> pvb.  One block per token.
// ---------------------------------------------------------------------------
__global__ __launch_bounds__(256) void rg_xm_ln_k(
    const float* __restrict__ x, const float* __restrict__ rgw,
    const float* __restrict__ rgb, const float* __restrict__ g,
    const float* __restrict__ b, const float* __restrict__ phw,
    const float* __restrict__ phb, const float* __restrict__ ps_p,
    float* __restrict__ xm, bf16_t* __restrict__ ainb,
    float* __restrict__ pvb, float* __restrict__ gs_out)
{
    int t = blockIdx.x, tid = threadIdx.x;
    __shared__ float xr[D_];
    __shared__ float red[256];
    __shared__ float rgsh[4];

    #pragma unroll
    for (int it = 0; it < 4; ++it) {
        int d = it * 256 + tid;
        xr[d] = x[(size_t)t * D_ + d];
    }
    __syncthreads();

    float a0 = 0.f, a1 = 0.f, a2 = 0.f, a3 = 0.f;
    #pragma unroll
    for (int it = 0; it < 4; ++it) {
        int d = it * 256 + tid;
        float xv = xr[d];
        float4 w = *(const float4*)(rgw + (size_t)d * 4);
        a0 += xv * w.x; a1 += xv * w.y; a2 += xv * w.z; a3 += xv * w.w;
    }
    float s0 = block_sum_(a0, red);
    float s1 = block_sum_(a1, red);
    float s2 = block_sum_(a2, red);
    float s3 = block_sum_(a3, red);
    if (tid == 0) {
        float r0 = sigmoidf_(s0 + rgb[0]);
        float r1 = sigmoidf_(s1 + rgb[1]);
        float r2 = sigmoidf_(s2 + rgb[2]);
        float r3 = sigmoidf_(s3 + rgb[3]);
        rgsh[0] = r0; rgsh[1] = r1; rgsh[2] = r2; rgsh[3] = r3;
        gs_out[(size_t)t * 4 + 0] = r0;
        gs_out[(size_t)t * 4 + 1] = r1;
        gs_out[(size_t)t * 4 + 2] = r2;
        gs_out[(size_t)t * 4 + 3] = r3;
    }
    __syncthreads();
    float factor = 1.0f + 0.025f * (rgsh[0] + rgsh[1] + rgsh[2] + rgsh[3]);

    float sm = 0.f, sq = 0.f;
    float vals[4];
    #pragma unroll
    for (int it = 0; it < 4; ++it) {
        int d = it * 256 + tid;
        float v = xr[d] * factor;
        vals[it] = v;
        xm[(size_t)t * D_ + d] = v;
        sm += v; sq += v * v;
    }
    float mean = block_sum_(sm, red) * (1.0f / D_);
    float msq  = block_sum_(sq, red) * (1.0f / D_);
    float rstd = rsqrtf(msq - mean * mean + 1e-5f);
    #pragma unroll
    for (int it = 0; it < 4; ++it) {
        int d = it * 256 + tid;
        float a = (vals[it] - mean) * rstd * g[d] + b[d];
        ainb[(size_t)t * D_ + d] = (bf16_t)a;
        xr[d] = a;                      // keep LN output for phase GEMV
    }
    __syncthreads();

    // phase GEMV: col c = tid&15, k-chunk grp = tid>>4 (64 k each)
    {
        int c = tid & 15, grp = tid >> 4;
        float acc = 0.f;
        int k0 = grp * 64;
        #pragma unroll
        for (int kk = 0; kk < 64; ++kk)
            acc += xr[k0 + kk] * phw[(size_t)(k0 + kk) * H_ + c];
        red[tid] = acc;
        __syncthreads();
        if (tid < 16) {
            float s = 0.f;
            #pragma unroll
            for (int gg = 0; gg < 16; ++gg) s += red[gg * 16 + tid];
            pvb[(size_t)t * H_ + tid] = tanhf_(ps_p[0] * (s + phb[tid]));
        }
    }
}

// ---------------------------------------------------------------------------
// LayerNorm over rows of D_; writes f32 (optional) and/or bf16 (optional).
// ---------------------------------------------------------------------------
__global__ __launch_bounds__(256) void ln_k(
    const float* __restrict__ in, const float* __restrict__ g,
    const float* __restrict__ b, float* __restrict__ outp,
    bf16_t* __restrict__ outb)
{
    int t = blockIdx.x, tid = threadIdx.x;
    __shared__ float red[256];
    float s1 = 0.f, s2 = 0.f;
    float vals[4];
    #pragma unroll
    for (int it = 0; it < 4; ++it) {
        int d = it * 256 + tid;
        float v = in[(size_t)t * D_ + d];
        vals[it] = v; s1 += v; s2 += v * v;
    }
    float mean = block_sum_(s1, red) * (1.0f / D_);
    float msq  = block_sum_(s2, red) * (1.0f / D_);
    float rstd = rsqrtf(msq - mean * mean + 1e-5f);
    #pragma unroll
    for (int it = 0; it < 4; ++it) {
        int d = it * 256 + tid;
        float v = (vals[it] - mean) * rstd * g[d] + b[d];
        if (outp) outp[(size_t)t * D_ + d] = v;
        if (outb) outb[(size_t)t * D_ + d] = (bf16_t)v;
    }
}

// ---------------------------------------------------------------------------
// bf16 MFMA GEMM (m97 structure + T2 source-swizzle): C = act(A @ B^T + bias)
//   A: bf16 [M][K] row-major; Bm: bf16 [N][K] row-major (k-contiguous).
//   global_load_lds dwordx4 staging. The GLOBAL source column is pre-swizzled
//   (scol = ((lane&7)^(lane>>3))*8) so the linear LDS write lands XOR-swizzled;
//   fragment ds_read_b128 uses chunk ^ (row&7) -> 2 lanes/bank (conflict-free).
// Tile 128xBN, BK=64; 256 threads = 4 waves; wave tile 64 x (BN/2).
// ---------------------------------------------------------------------------
template<int BN>
__global__ __launch_bounds__(256) void gemm_bf_k(
    const bf16_t* __restrict__ A, const bf16_t* __restrict__ Bm,
    const float* __restrict__ bias, const float* __restrict__ resid,
    float* __restrict__ C, bf16_t* __restrict__ Cb,
    int M, int N, int K, int MT, int GW,
    int act, const float* __restrict__ scale_ptr)
{
    constexpr int BM = 128;
    constexpr int BK = 64;
    constexpr int WN = BN / 32;      // n-frags per wave

    __shared__ alignas(16) bf16_t As[BM][BK];
    __shared__ alignas(16) bf16_t Bs[BN][BK];

    const int tid  = threadIdx.x;
    const int lane = tid & 63;
    const int w    = tid >> 6;

    // grouped block swizzle: m-fastest within an n-group (weight tile L2-resident)
    int per = MT * GW;
    int grp = blockIdx.x / per;
    int r   = blockIdx.x % per;
    int mi  = r % MT;
    int ni  = grp * GW + r / MT;
    const int bm = mi * BM;
    const int bn = ni * BN;

    const int wr = (w & 1) * 64;
    const int wc = (w >> 1) * (BN / 2);
    const int rlo = lane & 15, lhi = lane >> 4;
    const int srow = lane >> 3;                       // staging row in 8-row slab
    const int scol = ((lane & 7) ^ srow) * 8;         // pre-swizzled source col
    const int rsw  = rlo & 7;                         // read-side row swizzle

    f32x4 acc[4][WN];
    #pragma unroll
    for (int m = 0; m < 4; ++m)
        #pragma unroll
        for (int n = 0; n < WN; ++n) {
            f32x4 z = {0.f, 0.f, 0.f, 0.f};
            acc[m][n] = z;
        }

    for (int kt = 0; kt < K; kt += BK) {
        __syncthreads();
        // ---- stage A: 16 slabs of 8 rows, 4 per wave
        #pragma unroll
        for (int i = 0; i < 4; ++i) {
            int is = w * 4 + i;
            const bf16_t* gp = A + (size_t)(bm + is * 8 + srow) * K + kt + scol;
            GLOAD_LDS16(gp, &As[is * 8][0]);
        }
        // ---- stage B: BN/8 slabs, row-clamped for N edge
        #pragma unroll
        for (int i = 0; i < BN / 32; ++i) {
            int is = w * (BN / 32) + i;
            int row = bn + is * 8 + srow;
            if (row > N - 1) row = N - 1;
            const bf16_t* gp = Bm + (size_t)row * K + kt + scol;
            GLOAD_LDS16(gp, &Bs[is * 8][0]);
        }
        __syncthreads();

        // ---- compute: 2 k-halves of 32, swizzled fragment reads
        #pragma unroll
        for (int h2 = 0; h2 < 2; ++h2) {
            int ko = ((h2 * 4 + lhi) ^ rsw) * 8;
            bf16x8 af[4], bfr[WN];
            #pragma unroll
            for (int m = 0; m < 4; ++m)
                af[m] = *(const bf16x8*)(&As[wr + m * 16 + rlo][ko]);
            #pragma unroll
            for (int n = 0; n < WN; ++n)
                bfr[n] = *(const bf16x8*)(&Bs[wc + n * 16 + rlo][ko]);
            #pragma unroll
            for (int m = 0; m < 4; ++m)
                #pragma unroll
                for (int n = 0; n < WN; ++n)
                    acc[m][n] = __builtin_amdgcn_mfma_f32_16x16x32_bf16(
                        af[m], bfr[n], acc[m][n], 0, 0, 0);
        }
    }

    // ---- epilogue: C/D layout col = lane&15, row = (lane>>4)*4 + reg
    float scale = scale_ptr ? scale_ptr[0] : 1.0f;
    #pragma unroll
    for (int m = 0; m < 4; ++m) {
        #pragma unroll
        for (int n = 0; n < WN; ++n) {
            int col = bn + wc + n * 16 + rlo;
            if (col >= N) continue;
            #pragma unroll
            for (int i = 0; i < 4; ++i) {
                int row = bm + wr + m * 16 + lhi * 4 + i;
                float v = acc[m][n][i];
                if (bias) v += bias[col];
                if (act == 1)      v = gelu_exact_(v);
                else if (act == 2) v = tanhf_(scale * v);
                if (resid) v += resid[(size_t)row * N + col];
                if (C)  C[(size_t)row * N + col] = v;
                if (Cb) Cb[(size_t)row * N + col] = (bf16_t)v;
            }
        }
    }
}

// ---------------------------------------------------------------------------
// flash-style MFMA attention (bf16 qkv in, bf16 out). Grid: (L/64, H, B).
// Double-buffered K/V LDS, ONE barrier per KV tile; next tile's global loads
// are issued into registers BEFORE compute (T14 issue-early), written to the
// alternate buffer after compute. Race-free: iter t reads only buf[t&1];
// writes touch buf[(t+1)&1] whose last reads ended before iter t-1's barrier.
// ---------------------------------------------------------------------------
__global__ __launch_bounds__(256) void attn_mfma_k(
    const bf16_t* __restrict__ qkv, const float* __restrict__ pv,
    const float* __restrict__ res_scale_p, bf16_t* __restrict__ o)
{
    constexpr int QB = 64;
    constexpr int NB = 64;
    constexpr int NT = L_ / NB;

    __shared__ alignas(16) bf16_t Ks[2][NB][DH_];   // [buf][key][d]
    __shared__ alignas(16) bf16_t Vt[2][DH_][NB];   // [buf][d][key]
    __shared__ alignas(16) bf16_t Pl[4][16][NB];    // wave-private P tiles
    __shared__ float pvq_s[QB];
    __shared__ float pvk_s[2][NB];

    const int qt = blockIdx.x, h = blockIdx.y, b = blockIdx.z;
    const int tid = threadIdx.x;
    const int lane = tid & 63, w = tid >> 6;
    const int rlo = lane & 15, lhi = lane >> 4, l7 = lane & 7;
    const float rs = res_scale_p[0];

    const size_t rowbase = (size_t)(b * L_ + qt * QB);

    // staging geometry
    const int krow0 = tid >> 3,  kseg0 = tid & 7;          // K slab 0
    const int krow1 = krow0 + 32;                          // K slab 1
    const int vcol4 = (tid & 15) * 4, vkb = tid >> 4;      // V transpose

    // Q fragments (raw bf16; 1/8 scaling applied to scores later)
    bf16x8 qf[2];
    {
        const bf16_t* qrow = qkv + (rowbase + w * 16 + rlo) * 3072 + h * DH_;
        #pragma unroll
        for (int kk = 0; kk < 2; ++kk)
            qf[kk] = *(const bf16x8*)(qrow + kk * 32 + lhi * 8);
    }
    if (tid < QB) pvq_s[tid] = pv[(rowbase + tid) * H_ + h];

    // register staging buffers
    bf16x8 kreg0, kreg1;
    bf16x4 vreg[4];
    float pvkr = 0.f;

    #define STAGE_LOAD(k0)                                                         \
    {                                                                              \
        kreg0 = *(const bf16x8*)(qkv + (size_t)(b * L_ + (k0) + krow0) * 3072      \
                                 + 1024 + h * DH_ + kseg0 * 8);                    \
        kreg1 = *(const bf16x8*)(qkv + (size_t)(b * L_ + (k0) + krow1) * 3072      \
                                 + 1024 + h * DH_ + kseg0 * 8);                    \
        _Pragma("unroll")                                                          \
        for (int j = 0; j < 4; ++j)                                                \
            vreg[j] = *(const bf16x4*)(qkv + (size_t)(b * L_ + (k0) + vkb * 4 + j) \
                                       * 3072 + 2048 + h * DH_ + vcol4);           \
        if (tid < NB) pvkr = pv[(size_t)(b * L_ + (k0) + tid) * H_ + h];           \
    }

    #define STAGE_WRITE(bf)                                                        \
    {                                                                              \
        *(bf16x8*)(&Ks[bf][krow0][(kseg0 ^ (krow0 & 7)) * 8]) = kreg0;             \
        *(bf16x8*)(&Ks[bf][krow1][(kseg0 ^ (krow1 & 7)) * 8]) = kreg1;             \
        _Pragma("unroll")                                                          \
        for (int jj = 0; jj < 4; ++jj) {                                           \
            int col = vcol4 + jj;                                                  \
            bf16x4 vv;                                                             \
            _Pragma("unroll")                                                      \
            for (int j = 0; j < 4; ++j) vv[j] = vreg[j][jj];                       \
            *(bf16x4*)(&Vt[bf][col][((vkb >> 1) ^ (col & 7)) * 8 + (vkb & 1) * 4]) \
                = vv;                                                              \
        }                                                                          \
        if (tid < NB) pvk_s[bf][tid] = pvkr;                                       \
    }

    STAGE_LOAD(0);
    STAGE_WRITE(0);
    __syncthreads();
    float pvq_r[4];
    #pragma unroll
    for (int r = 0; r < 4; ++r) pvq_r[r] = pvq_s[w * 16 + lhi * 4 + r];

    float m_r[4], l_r[4];
    f32x4 acc_o[4];
    #pragma unroll
    for (int r = 0; r < 4; ++r) { m_r[r] = -1e30f; l_r[r] = 0.f; }
    #pragma unroll
    for (int n = 0; n < 4; ++n) {
        f32x4 z = {0.f, 0.f, 0.f, 0.f};
        acc_o[n] = z;
    }

    bf16_t* pw = &Pl[w][0][0];

    for (int t = 0; t < NT; ++t) {
        const int cur = t & 1;
        if (t + 1 < NT) STAGE_LOAD((t + 1) * NB);   // loads in flight over compute

        // ---- S = Q @ K^T
        f32x4 sacc[4];
        #pragma unroll
        for (int n = 0; n < 4; ++n) {
            f32x4 z = {0.f, 0.f, 0.f, 0.f};
            sacc[n] = z;
        }
        __builtin_amdgcn_s_setprio(1);
        #pragma unroll
        for (int kk = 0; kk < 2; ++kk) {
            int soff = ((kk * 4 + lhi) ^ l7) * 8;
            bf16x8 kf[4];
            #pragma unroll
            for (int n = 0; n < 4; ++n)
                kf[n] = *(const bf16x8*)(&Ks[cur][n * 16 + rlo][soff]);
            #pragma unroll
            for (int n = 0; n < 4; ++n)
                sacc[n] = __builtin_amdgcn_mfma_f32_16x16x32_bf16(
                    qf[kk], kf[n], sacc[n], 0, 0, 0);
        }
        __builtin_amdgcn_s_setprio(0);

        // ---- scale + phase bias + tile max (C: row q = lhi*4+r, col = n*16+rlo)
        float sv[4][4];
        float tmax[4] = {-1e30f, -1e30f, -1e30f, -1e30f};
        #pragma unroll
        for (int n = 0; n < 4; ++n) {
            float pvk = pvk_s[cur][n * 16 + rlo];
            #pragma unroll
            for (int r = 0; r < 4; ++r) {
                float dd = pvq_r[r] - pvk;
                float s = sacc[n][r] * 0.125f - rs * dd * dd;
                sv[n][r] = s;
                tmax[r] = fmaxf(tmax[r], s);
            }
        }
        #pragma unroll
        for (int st = 1; st < 16; st <<= 1)
            #pragma unroll
            for (int r = 0; r < 4; ++r)
                tmax[r] = fmaxf(tmax[r], __shfl_xor(tmax[r], st));

        // ---- online softmax update (fast exp)
        float tsum[4] = {0.f, 0.f, 0.f, 0.f};
        #pragma unroll
        for (int r = 0; r < 4; ++r) {
            float mn = fmaxf(m_r[r], tmax[r]);
            float sc = __expf(m_r[r] - mn);
            m_r[r] = mn;
            l_r[r] *= sc;
            #pragma unroll
            for (int n = 0; n < 4; ++n) acc_o[n][r] *= sc;
        }
        #pragma unroll
        for (int n = 0; n < 4; ++n) {
            int key = n * 16 + rlo;
            #pragma unroll
            for (int r = 0; r < 4; ++r) {
                float p = __expf(sv[n][r] - m_r[r]);
                tsum[r] += p;
                int q = lhi * 4 + r;
                pw[q * NB + (((key >> 3) ^ (q & 7)) * 8 + (key & 7))] = (bf16_t)p;
            }
        }
        #pragma unroll
        for (int st = 1; st < 16; st <<= 1)
            #pragma unroll
            for (int r = 0; r < 4; ++r)
                tsum[r] += __shfl_xor(tsum[r], st);
        #pragma unroll
        for (int r = 0; r < 4; ++r) l_r[r] += tsum[r];

        // ---- O += P @ V
        __builtin_amdgcn_s_setprio(1);
        #pragma unroll
        for (int kk = 0; kk < 2; ++kk) {
            int soff = ((kk * 4 + lhi) ^ l7) * 8;
            bf16x8 pa = *(const bf16x8*)(pw + rlo * NB + (((kk * 4 + lhi) ^ (rlo & 7)) * 8));
            bf16x8 vf[4];
            #pragma unroll
            for (int n = 0; n < 4; ++n)
                vf[n] = *(const bf16x8*)(&Vt[cur][n * 16 + rlo][soff]);
            #pragma unroll
            for (int n = 0; n < 4; ++n)
                acc_o[n] = __builtin_amdgcn_mfma_f32_16x16x32_bf16(
                    pa, vf[n], acc_o[n], 0, 0, 0);
        }
        __builtin_amdgcn_s_setprio(0);

        // ---- write next tile to alternate buffer, single barrier per tile
        if (t + 1 < NT) {
            STAGE_WRITE(cur ^ 1);
            __syncthreads();
        }
    }

    // ---- normalize and write bf16
    float inv[4];
    #pragma unroll
    for (int r = 0; r < 4; ++r) inv[r] = 1.0f / l_r[r];
    #pragma unroll
    for (int n = 0; n < 4; ++n)
        #pragma unroll
        for (int r = 0; r < 4; ++r)
            o[(rowbase + w * 16 + lhi * 4 + r) * D_ + h * DH_ + n * 16 + rlo] =
                (bf16_t)(acc_o[n][r] * inv[r]);

    #undef STAGE_LOAD
    #undef STAGE_WRITE
}

// ---------------------------------------------------------------------------
// boundary second layer: ss[t] = sigmoid(dot(h[t], w2) + b2). block per token.
// ---------------------------------------------------------------------------
__global__ __launch_bounds__(256) void bnd2_k(
    const float* __restrict__ hbuf, const float* __restrict__ w2,
    const float* __restrict__ b2, float* __restrict__ ss_out)
{
    int t = blockIdx.x, tid = threadIdx.x;
    __shared__ float red[256];
    float acc = 0.f;
    #pragma unroll
    for (int it = 0; it < 2; ++it) {
        int d = it * 256 + tid;
        acc += hbuf[(size_t)t * HID_ + d] * w2[d];
    }
    float s = block_sum_(acc, red);
    if (tid == 0) ss_out[t] = sigmoidf_(s + b2[0]);
}

// ---------------------------------------------------------------------------
// grammar/shock means over layers
// ---------------------------------------------------------------------------
__global__ __launch_bounds__(256) void means_k(
    const float* __restrict__ gs, const float* __restrict__ ss,
    float* __restrict__ gsm, float* __restrict__ ssm)
{
    int i = blockIdx.x * 256 + threadIdx.x;
    if (i < BL_ * 4) {
        float s = 0.f;
        #pragma unroll
        for (int l = 0; l < NLAYER; ++l) s += gs[(size_t)l * BL_ * 4 + i];
        gsm[i] = s * (1.0f / NLAYER);
    }
    if (i < BL_) {
        float s = 0.f;
        #pragma unroll
        for (int l = 0; l < NLAYER; ++l) s += ss[(size_t)l * BL_ + i];
        ssm[i] = s * (1.0f / NLAYER);
    }
}

// ---------------------------------------------------------------------------
// launcher
// ---------------------------------------------------------------------------
extern "C" void kernel_launch(void* const* d_in, const int* in_sizes, int n_in,
                              void* d_out, int out_size, void* d_ws, size_t ws_size,
                              hipStream_t stream) {
    const int*   ids       = (const int*)  d_in[0];
    const float* embed     = (const float*)d_in[1];
    const float* pos_enc   = (const float*)d_in[2];
    const float* rg_w      = (const float*)d_in[3];
    const float* rg_b      = (const float*)d_in[4];
    const float* qkv_w     = (const float*)d_in[5];
    const float* qkv_b     = (const float*)d_in[6];
    const float* out_w     = (const float*)d_in[7];
    const float* out_b     = (const float*)d_in[8];
    const float* ph_w      = (const float*)d_in[9];
    const float* ph_b      = (const float*)d_in[10];
    const float* res_scale = (const float*)d_in[11];
    const float* ph_scale  = (const float*)d_in[12];
    const float* ff1_w     = (const float*)d_in[13];
    const float* ff1_b     = (const float*)d_in[14];
    const float* ff2_w     = (const float*)d_in[15];
    const float* ff2_b     = (const float*)d_in[16];
    const float* n1_g      = (const float*)d_in[17];
    const float* n1_b      = (const float*)d_in[18];
    const float* n2_g      = (const float*)d_in[19];
    const float* n2_b      = (const float*)d_in[20];
    const float* bnd_w1    = (const float*)d_in[21];
    const float* bnd_b1    = (const float*)d_in[22];
    const float* bnd_w2    = (const float*)d_in[23];
    const float* bnd_b2    = (const float*)d_in[24];
    const float* fn_g      = (const float*)d_in[25];
    const float* fn_b      = (const float*)d_in[26];

    float* out = (float*)d_out;
    float* ws  = (float*)d_ws;

    // workspace layout (float slots). bf16 buffers occupy half-slots.
    const size_t M1 = 1024 * 1024;
    float*  x    = ws;                                  // [0, 2M)
    float*  xm   = ws + 2 * M1;                         // [2M, 4M)
    float*  bndh = ws + 4 * M1;                         // [4M, 5M)
    float*  pvb  = ws + 5 * M1;                         // 32K floats
    bf16_t* ainb = (bf16_t*)(ws + 5 * M1 + M1 / 4);     // 2048x1024 bf16 (1M slots)
    bf16_t* aob  = (bf16_t*)(ws + 6 * M1 + M1 / 4);     // 2048x1024 bf16
    bf16_t* xb   = (bf16_t*)(ws + 7 * M1 + M1 / 4);     // 2048x1024 bf16
    bf16_t* qkvb = (bf16_t*)(ws + 8 * M1 + M1 / 4);     // 2048x3072 bf16 (3M slots)
    bf16_t* ffhb = (bf16_t*)(ws + 11 * M1 + M1 / 4);    // 2048x4096 bf16 (4M slots)
    float*  wT   = ws + 15 * M1 + M1 / 4;               // per-layer bf16 W^T scratch
    bf16_t* qkvT = (bf16_t*)(wT);                       // 3072x1024
    bf16_t* outT = (bf16_t*)(wT + 1572864);             // 1024x1024
    bf16_t* ff1T = (bf16_t*)(wT + 2097152);             // 4096x1024
    bf16_t* ff2T = (bf16_t*)(wT + 4194304);             // 1024x4096
    bf16_t* bndT = (bf16_t*)(wT + 6291456);             // 512x1024 (converted once)
    bf16_t* embB = qkvb;                                // embed bf16, aliases dead bufs

    // output offsets (floats, concatenated return order)
    const size_t o_logits = 0;
    const size_t o_x      = (size_t)BL_ * V_;
    const size_t o_gsm    = o_x + (size_t)BL_ * D_;
    const size_t o_ssm    = o_gsm + (size_t)BL_ * 4;
    const size_t o_gs     = o_ssm + (size_t)BL_;
    const size_t o_ss     = o_gs + (size_t)NLAYER * BL_ * 4;

    embed_k<<<BL_, 256, 0, stream>>>(ids, embed, pos_enc, x);

    // boundary W1 -> bf16 [512][1024], once
    tcw_k<<<512, 256, 0, stream>>>(
        bnd_w1, bndT, D_, HID_, 512,
        bnd_w1, bndT, D_, HID_, 512,
        bnd_w1, bndT, D_, HID_, 512,
        bnd_w1, bndT, D_, HID_, 512);

    const int MT = BL_ / 128;  // 16 m-tiles

    for (int i = 0; i < NLAYER; ++i) {
        // convert this layer's 4 weights to bf16 W^T (one dispatch)
        tcw_k<<<12288, 256, 0, stream>>>(
            qkv_w + (size_t)i * D_ * 3 * D_,    qkvT, D_,     3 * D_, 3072,
            out_w + (size_t)i * D_ * D_,        outT, D_,     D_,     4096,
            ff1_w + (size_t)i * D_ * 4 * D_,    ff1T, D_,     4 * D_, 8192,
            ff2_w + (size_t)i * 4 * D_ * D_,    ff2T, 4 * D_, D_,     12288);

        rg_xm_ln_k<<<BL_, 256, 0, stream>>>(
            x, rg_w + (size_t)i * D_ * 4, rg_b + (size_t)i * 4,
            n1_g + (size_t)i * D_, n1_b + (size_t)i * D_,
            ph_w + (size_t)i * D_ * H_, ph_b + (size_t)i * H_, ph_scale + i,
            xm, ainb, pvb, out + o_gs + (size_t)i * BL_ * 4);

        // QKV: 2048 x 3072 x 1024 -> qkvb (bf16)
        gemm_bf_k<128><<<MT * 24, 256, 0, stream>>>(
            ainb, qkvT, qkv_b + (size_t)i * 3 * D_, nullptr,
            nullptr, qkvb, BL_, 3 * D_, D_, MT, 4, 0, nullptr);

        dim3 ga(L_ / 64, H_, B_);
        attn_mfma_k<<<ga, 256, 0, stream>>>(qkvb, pvb, res_scale + i, aob);

        // out-proj: 2048 x 1024 x 1024 (+xm resid) -> x (f32)
        gemm_bf_k<64><<<MT * 16, 256, 0, stream>>>(
            aob, outT, out_b + (size_t)i * D_, xm,
            x, nullptr, BL_, D_, D_, MT, 4, 0, nullptr);

        ln_k<<<BL_, 256, 0, stream>>>(x, n2_g + (size_t)i * D_, n2_b + (size_t)i * D_,
                                      nullptr, ainb);

        // FF1: 2048 x 4096 x 1024, exact GELU -> ffhb (bf16)
        gemm_bf_k<128><<<MT * 32, 256, 0, stream>>>(
            ainb, ff1T, ff1_b + (size_t)i * 4 * D_, nullptr,
            nullptr, ffhb, BL_, 4 * D_, D_, MT, 4, 1, nullptr);

        // FF2: 2048 x 1024 x 4096 (+x resid) -> x (f32) and xb (bf16)
        gemm_bf_k<64><<<MT * 16, 256, 0, stream>>>(
            ffhb, ff2T, ff2_b + (size_t)i * D_, x,
            x, xb, BL_, D_, 4 * D_, MT, 4, 0, nullptr);

        // boundary-1: 2048 x 512 x 1024, tanh -> bndh (f32)
        gemm_bf_k<64><<<MT * 8, 256, 0, stream>>>(
            xb, bndT, bnd_b1, nullptr,
            bndh, nullptr, BL_, HID_, D_, MT, 4, 2, nullptr);

        bnd2_k<<<BL_, 256, 0, stream>>>(bndh, bnd_w2, bnd_b2, out + o_ss + (size_t)i * BL_);
    }

    // final LN -> f32 output tensor + bf16 logits operand
    ln_k<<<BL_, 256, 0, stream>>>(x, fn_g, fn_b, out + o_x, xb);

    // embed -> bf16 (aliases dead qkvb/ffhb/wT region)
    cvtb_k<<<4096, 256, 0, stream>>>(embed, embB, V_ * D_ / 8);

    // tied head: 2048 x 30000 x 1024
    gemm_bf_k<128><<<MT * 235, 256, 0, stream>>>(
        xb, embB, nullptr, nullptr,
        out + o_logits, nullptr, BL_, V_, D_, MT, 5, 0, nullptr);

    means_k<<<(BL_ * 4 + 255) / 256, 256, 0, stream>>>(
        out + o_gs, out + o_ss, out + o_gsm, out + o_ssm);
}